// Round 11
// baseline (374.220 us; speedup 1.0000x reference)
//
#include <hip/hip_runtime.h>

#define BB 64
#define NN 1000
#define NP 1024
#define DD 512
#define HH 8
#define SS 20
#define NEGV -1e9f

typedef float v4f __attribute__((ext_vector_type(4)));
typedef short v8s __attribute__((ext_vector_type(8)));
typedef int   v8i __attribute__((ext_vector_type(8)));
typedef int   v4i __attribute__((ext_vector_type(4)));
typedef unsigned char uchar;
typedef unsigned long long ulong_t;

static __device__ __forceinline__ short f2bf(float f) {
    unsigned u = __builtin_bit_cast(unsigned, f);
    u = (u + 0x7fffu + ((u >> 16) & 1u)) >> 16;
    return (short)u;
}
static __device__ __forceinline__ float bf2f(short s) {
    unsigned u = ((unsigned)(unsigned short)s) << 16;
    return __builtin_bit_cast(float, u);
}
static __device__ __forceinline__ uchar f2fp8(float f) {
    return (uchar)(__builtin_amdgcn_cvt_pk_fp8_f32(f, 0.f, 0, false) & 0xff);
}

// async global->LDS, 16B per lane; lds dest = wave-uniform base + lane*16
static __device__ __forceinline__ void gld16(const void* g, void* l) {
    __builtin_amdgcn_global_load_lds(
        (const __attribute__((address_space(1))) void*)(g),
        (__attribute__((address_space(3))) void*)(l),
        16, 0, 0);
}

// ---------------- K0 (merged prep): W_kvl^T->fp8, W_out^T->bf16, emb->fp8 ----------------
__global__ void prep(const float* __restrict__ Wkvl, uchar* __restrict__ Wt8,
                     const float* __restrict__ Wout, short* __restrict__ Wot,
                     const float* __restrict__ emb, int* __restrict__ emb8) {
    __shared__ float t[32][33];
    int bid = blockIdx.x, tid = threadIdx.x;
    if (bid < 768) {           // transpose_fp8: W_kvl [512][1536] -> Wt8 [1536][512]
        int c0 = (bid % 48) * 32, r0 = (bid / 48) * 32;
        int x = tid & 31, y = tid >> 5;
        for (int k = 0; k < 32; k += 8)
            t[y + k][x] = Wkvl[(long)(r0 + y + k) * 1536 + c0 + x];
        __syncthreads();
        for (int k = 0; k < 32; k += 8)
            Wt8[(long)(c0 + y + k) * 512 + r0 + x] = f2fp8(t[x][y + k]);
    } else if (bid < 1024) {   // transpose_bf16: W_out [512][512] -> Wot [512][512]
        int bb = bid - 768;
        int c0 = (bb & 15) * 32, r0 = (bb >> 4) * 32;
        int x = tid & 31, y = tid >> 5;
        for (int k = 0; k < 32; k += 8)
            t[y + k][x] = Wout[(long)(r0 + y + k) * 512 + c0 + x];
        __syncthreads();
        for (int k = 0; k < 32; k += 8)
            Wot[(long)(c0 + y + k) * 512 + r0 + x] = f2bf(t[x][y + k]);
    } else {                   // cvt_fp8: emb f32 -> fp8, 8 elems/thread
        int i = (bid - 1024) * 256 + tid;
        long o = (long)i * 8;
        v4f a = *(const v4f*)(emb + o);
        v4f b = *(const v4f*)(emb + o + 4);
        int lo = __builtin_amdgcn_cvt_pk_fp8_f32(a.x, a.y, 0, false);
        lo = __builtin_amdgcn_cvt_pk_fp8_f32(a.z, a.w, lo, true);
        int hi = __builtin_amdgcn_cvt_pk_fp8_f32(b.x, b.y, 0, false);
        hi = __builtin_amdgcn_cvt_pk_fp8_f32(b.z, b.w, hi, true);
        int2 r; r.x = lo; r.y = hi;
        *(int2*)(emb8 + i * 2) = r;
    }
}

// ---------------- K1: kvl8[64000][1536] = emb8 @ Wt8  (MX-fp8, unit scales) ----------------
// 128x128 tile, BK=128, 4 waves (2x2), double-buffered 64KiB LDS (R8-proven, 82.4us).
__global__ __launch_bounds__(256) void gemm_kvl(const uchar* __restrict__ emb8,
                                                const uchar* __restrict__ Wt8,
                                                uchar* __restrict__ kvl8) {
    extern __shared__ __align__(16) uchar smem[];
    uchar* As0 = smem;           // 2 x 16384 (A: 128 rows x 128B)
    uchar* Bs0 = smem + 32768;   // 2 x 16384 (B: 128 rows x 128B)
    int tid = threadIdx.x;
    // XCD swizzle: nwg=6000, divisible by 8 -> simple bijective form
    int id = blockIdx.x;
    int wgid = (id & 7) * 750 + (id >> 3);
    int m_idx = wgid / 12, n_idx = wgid - m_idx * 12;
    int m0 = m_idx * 128, n0 = n_idx * 128;
    int wid = tid >> 6, lane = tid & 63, quad = lane >> 4, l16 = lane & 15;
    int wm = wid & 1, wn = wid >> 1;   // wave tile: 64(m) x 64(n)
    const uchar* Ag = emb8 + (long)m0 * 512;
    const uchar* Bg = Wt8 + (long)n0 * 512;
    int rsub = lane >> 3;
    int kc = ((lane & 7) ^ rsub) * 16;   // pre-swizzled global source chunk

    v4f acc[4][4] = {};

    auto stageAB = [&](int bi, int kk) {
        #pragma unroll
        for (int p = 0; p < 4; ++p) {
            int rl = wid * 32 + p * 8;
            gld16(Ag + (long)(rl + rsub) * 512 + kk + kc, As0 + bi * 16384 + rl * 128);
        }
        #pragma unroll
        for (int p = 0; p < 4; ++p) {
            int rl = wid * 32 + p * 8;
            gld16(Bg + (long)(rl + rsub) * 512 + kk + kc, Bs0 + bi * 16384 + rl * 128);
        }
    };
    auto ldfrag = [&](const uchar* base, int row) -> v8i {
        int c0 = (quad * 2) ^ (row & 7);
        v4i lo = *(const v4i*)(base + row * 128 + c0 * 16);
        v4i hi = *(const v4i*)(base + row * 128 + (c0 ^ 1) * 16);
        return __builtin_shufflevector(lo, hi, 0, 1, 2, 3, 4, 5, 6, 7);
    };

    stageAB(0, 0);
    stageAB(1, 128);
    asm volatile("s_waitcnt vmcnt(8)" ::: "memory");
    __builtin_amdgcn_s_barrier();
    __builtin_amdgcn_sched_barrier(0);

    v8i af[4], bf[4];
    #pragma unroll
    for (int t = 0; t < 4; ++t) {
        int cur = t & 1;
        const uchar* ab = As0 + cur * 16384;
        const uchar* bb = Bs0 + cur * 16384;
        #pragma unroll
        for (int i = 0; i < 4; ++i) af[i] = ldfrag(ab, wm * 64 + i * 16 + l16);
        #pragma unroll
        for (int j = 0; j < 4; ++j) bf[j] = ldfrag(bb, wn * 64 + j * 16 + l16);
        __builtin_amdgcn_s_setprio(1);
        #pragma unroll
        for (int i = 0; i < 4; ++i)
            #pragma unroll
            for (int j = 0; j < 2; ++j)
                acc[i][j] = __builtin_amdgcn_mfma_scale_f32_16x16x128_f8f6f4(
                    af[i], bf[j], acc[i][j], 0, 0, 0, 0x7f7f7f7f, 0, 0x7f7f7f7f);
        __builtin_amdgcn_s_setprio(0);
        asm volatile("s_waitcnt lgkmcnt(0)" ::: "memory");
        __builtin_amdgcn_s_barrier();
        if (t < 2) stageAB(cur, (t + 2) * 128);
        __builtin_amdgcn_s_setprio(1);
        #pragma unroll
        for (int i = 0; i < 4; ++i)
            #pragma unroll
            for (int j = 2; j < 4; ++j)
                acc[i][j] = __builtin_amdgcn_mfma_scale_f32_16x16x128_f8f6f4(
                    af[i], bf[j], acc[i][j], 0, 0, 0, 0x7f7f7f7f, 0, 0x7f7f7f7f);
        __builtin_amdgcn_s_setprio(0);
        if (t < 3) {
            if (t < 2) asm volatile("s_waitcnt vmcnt(8)" ::: "memory");
            else       asm volatile("s_waitcnt vmcnt(0)" ::: "memory");
            __builtin_amdgcn_s_barrier();
            __builtin_amdgcn_sched_barrier(0);
        }
    }
    __syncthreads();

    short* rp = (short*)smem;
    short* r = rp + wid * (16 * 72);
    #pragma unroll
    for (int i = 0; i < 4; ++i) {
        #pragma unroll
        for (int jj = 0; jj < 4; ++jj)
            #pragma unroll
            for (int rr = 0; rr < 4; ++rr)
                r[(quad * 4 + rr) * 72 + jj * 16 + l16] = f2bf(acc[i][jj][rr]);
        #pragma unroll
        for (int h = 0; h < 2; ++h) {
            int rowl = h * 8 + (lane >> 3);
            int colc = (lane & 7) * 8;
            v8s val = *(const v8s*)(r + rowl * 72 + colc);
            int lo = __builtin_amdgcn_cvt_pk_fp8_f32(bf2f(val[0]), bf2f(val[1]), 0, false);
            lo = __builtin_amdgcn_cvt_pk_fp8_f32(bf2f(val[2]), bf2f(val[3]), lo, true);
            int hi = __builtin_amdgcn_cvt_pk_fp8_f32(bf2f(val[4]), bf2f(val[5]), 0, false);
            hi = __builtin_amdgcn_cvt_pk_fp8_f32(bf2f(val[6]), bf2f(val[7]), hi, true);
            int2 st; st.x = lo; st.y = hi;
            *(int2*)(kvl8 + (long)(m0 + wm * 64 + i * 16 + rowl) * 1536 +
                     n0 + wn * 64 + colc) = st;
        }
    }
}

// ---------------- K2: pack K,V into MFMA-fragment-ready layouts (R9-proven) ----------------
__global__ void pack_kv(const uchar* __restrict__ kvl8, uchar* __restrict__ Kf,
                        uchar* __restrict__ Vf) {
    int bh = blockIdx.x, b = bh >> 3, h = bh & 7;
    int g = blockIdx.y;            // node group: nodes g*64 .. g*64+63
    __shared__ uchar Kl[64][72];
    __shared__ uchar VT[64][72];
    int tid = threadIdx.x;
    int node_l = tid >> 2, chunk = (tid & 3) * 16;
    int gn = g * 64 + node_l;
    int ncl = gn < NN ? gn : NN - 1;   // clamp: padded nodes masked downstream
    const uchar* rowp = kvl8 + ((long)b * NN + ncl) * 1536 + h * 64;
    *(v4i*)&Kl[node_l][chunk] = *(const v4i*)(rowp + chunk);
    {
        const uchar* vp = rowp + 512 + chunk;
        ulong_t v0 = *(const ulong_t*)(vp);
        ulong_t v1 = *(const ulong_t*)(vp + 8);
        uchar* b0p = (uchar*)&v0; uchar* b1p = (uchar*)&v1;
        #pragma unroll
        for (int j = 0; j < 8; ++j) VT[chunk + j][node_l] = b0p[j];
        #pragma unroll
        for (int j = 0; j < 8; ++j) VT[chunk + 8 + j][node_l] = b1p[j];
    }
    __syncthreads();
    int wid = tid >> 6, lane = tid & 63, l16 = lane & 15, quad = lane >> 4;
    #pragma unroll
    for (int ks = 0; ks < 2; ++ks) {
        ulong_t frag = *(const ulong_t*)&Kl[wid * 16 + l16][ks * 32 + quad * 8];
        *(ulong_t*)(Kf + (((long)bh * 64 + g * 4 + wid) * 2 + ks) * 512 + lane * 8) = frag;
    }
    #pragma unroll
    for (int sub = 0; sub < 2; ++sub) {
        ulong_t frag = *(const ulong_t*)&VT[wid * 16 + l16][sub * 32 + quad * 8];
        *(ulong_t*)(Vf + (((long)bh * 4 + wid) * 32 + g * 2 + sub) * 512 + lane * 8) = frag;
    }
}

// ---------------- K3: fused QK^T -> masked softmax -> PV (fp8, 512 threads) ----------------
#define CST 1036  // cmp row stride (shorts): 518 words/row -> conflict-free frag reads
__global__ __launch_bounds__(512) void attn_fused(const float* __restrict__ q,
                                                  const uchar* __restrict__ Kf,
                                                  const uchar* __restrict__ Vf,
                                                  const int* __restrict__ mask,
                                                  float* __restrict__ heads) {
    int b = blockIdx.x, h = blockIdx.y;
    __shared__ __align__(16) uchar qs[32 * 72];
    __shared__ __align__(16) short cmp[SS * CST];
    int tid = threadIdx.x, wid = tid >> 6, lane = tid & 63, quad = lane >> 4, l16 = lane & 15;
    for (int i = tid; i < 32 * 64; i += 512) {
        int row = i >> 6, col = i & 63;
        float v = (row < SS) ? q[((long)b * SS + row) * DD + h * 64 + col] : 0.f;
        qs[row * 72 + col] = f2fp8(v);
    }
    __syncthreads();
    long af[2][2];
    #pragma unroll
    for (int mt = 0; mt < 2; ++mt)
        #pragma unroll
        for (int ks = 0; ks < 2; ++ks)
            af[mt][ks] = *(const long*)(qs + (mt * 16 + l16) * 72 + ks * 32 + quad * 8);
    const uchar* kfb = Kf + ((long)(b * HH + h) * 64) * 1024;
    for (int t = 0; t < 8; ++t) {
        int nt = wid * 8 + t;
        long b0 = *(const long*)(kfb + (long)nt * 1024 + lane * 8);
        long b1 = *(const long*)(kfb + (long)nt * 1024 + 512 + lane * 8);
        #pragma unroll
        for (int mt = 0; mt < 2; ++mt) {
            v4f a = {};
            a = __builtin_amdgcn_mfma_f32_16x16x32_fp8_fp8(af[mt][0], b0, a, 0, 0, 0);
            a = __builtin_amdgcn_mfma_f32_16x16x32_fp8_fp8(af[mt][1], b1, a, 0, 0, 0);
            #pragma unroll
            for (int r = 0; r < 4; ++r) {
                int s = mt * 16 + quad * 4 + r;
                if (s < SS) cmp[s * CST + nt * 16 + l16] = f2bf(a[r] * 0.125f);
            }
        }
    }
    __syncthreads();
    for (int s = wid; s < SS; s += 8) {
        const int* mr = mask + ((long)b * SS + s) * NN;
        float x[16];
        float mx = NEGV;
        #pragma unroll
        for (int i = 0; i < 16; ++i) {
            int n = lane + 64 * i;
            float v = bf2f(cmp[s * CST + n]);
            bool feas = (n < NN) && (mr[n < NN ? n : 0] != 0);
            x[i] = feas ? v : NEGV;
            mx = fmaxf(mx, x[i]);
        }
        for (int off = 32; off; off >>= 1) mx = fmaxf(mx, __shfl_xor(mx, off));
        float sum = 0.f;
        #pragma unroll
        for (int i = 0; i < 16; ++i) { x[i] = __expf(x[i] - mx); sum += x[i]; }
        for (int off = 32; off; off >>= 1) sum += __shfl_xor(sum, off);
        float inv = 1.0f / sum;
        uchar* pr = (uchar*)cmp + (long)s * (CST * 2);
        #pragma unroll
        for (int i = 0; i < 16; ++i) pr[lane + 64 * i] = f2fp8(x[i] * inv);
    }
    __syncthreads();
    int mt = wid & 1, dt = wid >> 1;  // dt in 0..3
    int srow = mt * 16 + l16; if (srow > SS - 1) srow = SS - 1;
    const uchar* ap = (const uchar*)cmp + (long)srow * (CST * 2) + quad * 8;
    const uchar* vfb = Vf + (((long)(b * HH + h) * 4 + dt) * 32) * 512;
    v4f a0 = {}, a1 = {}, a2 = {}, a3 = {};
    for (int k0s = 0; k0s < 32; k0s += 4) {
        a0 = __builtin_amdgcn_mfma_f32_16x16x32_fp8_fp8(
            *(const long*)(ap + k0s * 32),
            *(const long*)(vfb + (long)k0s * 512 + lane * 8), a0, 0, 0, 0);
        a1 = __builtin_amdgcn_mfma_f32_16x16x32_fp8_fp8(
            *(const long*)(ap + (k0s + 1) * 32),
            *(const long*)(vfb + (long)(k0s + 1) * 512 + lane * 8), a1, 0, 0, 0);
        a2 = __builtin_amdgcn_mfma_f32_16x16x32_fp8_fp8(
            *(const long*)(ap + (k0s + 2) * 32),
            *(const long*)(vfb + (long)(k0s + 2) * 512 + lane * 8), a2, 0, 0, 0);
        a3 = __builtin_amdgcn_mfma_f32_16x16x32_fp8_fp8(
            *(const long*)(ap + (k0s + 3) * 32),
            *(const long*)(vfb + (long)(k0s + 3) * 512 + lane * 8), a3, 0, 0, 0);
    }
    v4f accv = (a0 + a1) + (a2 + a3);
    #pragma unroll
    for (int r = 0; r < 4; ++r) {
        int s = mt * 16 + quad * 4 + r;
        if (s < SS)
            heads[((long)b * SS + s) * DD + h * 64 + dt * 16 + l16] = accv[r];
    }
}

// ---------------- K4 (fused): glimpse = heads@W_out -> logits vs logit_k -> tanh/mask
// ---------------- -> log_softmax -> (s b) transposed store.  One block per b. ----------------
// LDS: As (heads/glimpse bf16, 32x520 shorts, reused) + Gs (fp8 32x520) + Lg (f32 20x1040).
__global__ __launch_bounds__(512) void head_out(const float* __restrict__ heads,
                                                const short* __restrict__ Wot,
                                                const uchar* __restrict__ kvl8,
                                                const int* __restrict__ mask,
                                                float* __restrict__ out) {
    extern __shared__ __align__(16) uchar hsm[];
    short* As = (short*)hsm;                    // 32*520 shorts = 33,280 B
    uchar* Gs = hsm + 33280;                    // 32*520 bytes  = 16,640 B
    float* Lg = (float*)(hsm + 33280 + 16640);  // 20*1040 f32   = 83,200 B
    int b = blockIdx.x;
    int tid = threadIdx.x, wid = tid >> 6, lane = tid & 63, quad = lane >> 4, l16 = lane & 15;

    // ---- phase 1a: stage heads[b] (20x512 f32 -> bf16), rows 20..31 zero ----
    for (int u = tid; u < 32 * 128; u += 512) {
        int row = u >> 7, c4 = (u & 127) * 4;
        short4 s4;
        if (row < SS) {
            v4f a = *(const v4f*)(heads + ((long)b * SS + row) * 512 + c4);
            s4.x = f2bf(a.x); s4.y = f2bf(a.y); s4.z = f2bf(a.z); s4.w = f2bf(a.w);
        } else { s4.x = 0; s4.y = 0; s4.z = 0; s4.w = 0; }
        *(short4*)(As + row * 520 + c4) = s4;
    }
    __syncthreads();

    // ---- phase 1b: glimpse = heads @ W_out (bf16 MFMA); wave wid owns cols wid*64..+63 ----
    int n0w = wid * 64;
    v4f acc[2][4] = {};
    for (int kk = 0; kk < 512; kk += 32) {
        v8s afr[2], bfr[4];
        #pragma unroll
        for (int m = 0; m < 2; ++m)
            afr[m] = *(const v8s*)(As + (m * 16 + l16) * 520 + kk + quad * 8);
        #pragma unroll
        for (int j = 0; j < 4; ++j)
            bfr[j] = *(const v8s*)(Wot + (long)(n0w + j * 16 + l16) * 512 + kk + quad * 8);
        #pragma unroll
        for (int m = 0; m < 2; ++m)
            #pragma unroll
            for (int j = 0; j < 4; ++j)
                acc[m][j] = __builtin_amdgcn_mfma_f32_16x16x32_bf16(afr[m], bfr[j], acc[m][j], 0, 0, 0);
    }
    __syncthreads();   // all As reads done -> safe to overwrite with glimpse
    #pragma unroll
    for (int m = 0; m < 2; ++m)
        #pragma unroll
        for (int j = 0; j < 4; ++j)
            #pragma unroll
            for (int r = 0; r < 4; ++r)
                As[(m * 16 + quad * 4 + r) * 520 + n0w + j * 16 + l16] = f2bf(acc[m][j][r]);
    __syncthreads();

    // ---- phase 2a: pack glimpse bf16 -> fp8 (Gs) ----
    for (int u = tid; u < 32 * 128; u += 512) {
        int row = u >> 7, c4 = (u & 127) * 4;
        short4 s4 = *(const short4*)(As + row * 520 + c4);
        int pk = __builtin_amdgcn_cvt_pk_fp8_f32(bf2f(s4.x), bf2f(s4.y), 0, false);
        pk = __builtin_amdgcn_cvt_pk_fp8_f32(bf2f(s4.z), bf2f(s4.w), pk, true);
        *(int*)(Gs + row * 520 + c4) = pk;
    }
    __syncthreads();

    // ---- phase 2b: logits = (glimpse . logit_k^T)/sqrt(512); 8 waves x 8 n-tiles ----
    const float scale = 0.04419417382415922f;  // 1/sqrt(512)
    for (int g = 0; g < 8; ++g) {
        int nt = wid * 8 + g;
        int n = nt * 16 + l16;
        int ncl = n < NN ? n : NN - 1;
        const uchar* kp = kvl8 + ((long)b * NN + ncl) * 1536 + 1024 + quad * 8;
        v4f acc2[2] = {};
        for (int k = 0; k < 16; ++k) {
            long bfr = *(const long*)(kp + k * 32);
            #pragma unroll
            for (int m = 0; m < 2; ++m) {
                long afr2 = *(const long*)(Gs + (m * 16 + l16) * 520 + k * 32 + quad * 8);
                acc2[m] = __builtin_amdgcn_mfma_f32_16x16x32_fp8_fp8(afr2, bfr, acc2[m], 0, 0, 0);
            }
        }
        #pragma unroll
        for (int m = 0; m < 2; ++m)
            #pragma unroll
            for (int r = 0; r < 4; ++r) {
                int s = m * 16 + quad * 4 + r;
                if (s < SS) Lg[s * 1040 + nt * 16 + l16] = acc2[m][r] * scale;
            }
    }
    __syncthreads();

    // ---- phase 3: per-row tanh clip + mask + log_softmax + transposed store ----
    for (int s = wid; s < SS; s += 8) {
        const int* mr = mask + ((long)b * SS + s) * NN;
        float x[16];
        float mx = NEGV;
        #pragma unroll
        for (int i = 0; i < 16; ++i) {
            int n = lane + 64 * i;
            float t = 10.f * tanhf(Lg[s * 1040 + n]);
            bool feas = (n < NN) && (mr[n < NN ? n : 0] != 0);
            x[i] = feas ? t : NEGV;
            mx = fmaxf(mx, x[i]);
        }
        for (int off = 32; off; off >>= 1) mx = fmaxf(mx, __shfl_xor(mx, off));
        float sum = 0.f;
        #pragma unroll
        for (int i = 0; i < 16; ++i) sum += __expf(x[i] - mx);
        for (int off = 32; off; off >>= 1) sum += __shfl_xor(sum, off);
        float lse = mx + __logf(sum);
        float* orow = out + ((long)s * BB + b) * NN;
        #pragma unroll
        for (int i = 0; i < 16; ++i) {
            int n = lane + 64 * i;
            if (n < NN) orow[n] = x[i] - lse;
        }
    }
}

extern "C" void kernel_launch(void* const* d_in, const int* in_sizes, int n_in,
                              void* d_out, int out_size, void* d_ws, size_t ws_size,
                              hipStream_t stream) {
    const float* emb  = (const float*)d_in[0];
    const float* q    = (const float*)d_in[1];
    const int*   mask = (const int*)d_in[2];
    const float* Wkvl = (const float*)d_in[3];
    const float* Wout = (const float*)d_in[4];
    float* out = (float*)d_out;

    char* ws = (char*)d_ws;
    uchar* kvl8    = (uchar*)ws; ws += (size_t)64000 * 1536;
    uchar* Vf      = (uchar*)ws; ws += (size_t)512 * 64 * NP;      // 33.55 MB
    uchar* Wt8     = (uchar*)ws; ws += (size_t)1536 * 512;
    uchar* emb8    = (uchar*)ws; ws += (size_t)64000 * 512;
    short* Wot     = (short*)ws; ws += (size_t)512 * 512 * 2;
    float* heads   = (float*)ws; ws += (size_t)BB * SS * DD * 4;

    // Kf overlays Wt8+emb8 (both dead after gemm_kvl):
    // Kf = 512bh*64nt*2ks*512B = 33,554,432B == Wt8(786,432)+emb8(32,768,000) exactly.
    uchar* Kf = Wt8;

    static int s_attr_done = 0;
    if (!s_attr_done) {
        hipFuncSetAttribute(reinterpret_cast<const void*>(gemm_kvl),
                            hipFuncAttributeMaxDynamicSharedMemorySize, 65536);
        hipFuncSetAttribute(reinterpret_cast<const void*>(head_out),
                            hipFuncAttributeMaxDynamicSharedMemorySize, 133120);
        s_attr_done = 1;
    }

    prep<<<dim3(1024 + 16000), 256, 0, stream>>>(Wkvl, Wt8, Wout, Wot, emb, (int*)emb8);
    gemm_kvl<<<dim3(6000), 256, 65536, stream>>>(emb8, Wt8, kvl8);
    pack_kv<<<dim3(512, 16), 256, 0, stream>>>(kvl8, Kf, Vf);
    attn_fused<<<dim3(BB, HH), 512, 0, stream>>>(q, Kf, Vf, mask, heads);
    head_out<<<dim3(BB), 512, 133120, stream>>>(heads, Wot, kvl8, mask, out);
}

// Round 13
// 347.259 us; speedup vs baseline: 1.0776x; 1.0776x over previous
//
#include <hip/hip_runtime.h>

#define BB 64
#define NN 1000
#define NP 1024
#define DD 512
#define HH 8
#define SS 20
#define NEGV -1e9f

typedef float v4f __attribute__((ext_vector_type(4)));
typedef short v8s __attribute__((ext_vector_type(8)));
typedef int   v8i __attribute__((ext_vector_type(8)));
typedef int   v4i __attribute__((ext_vector_type(4)));
typedef unsigned char uchar;
typedef unsigned long long ulong_t;

static __device__ __forceinline__ short f2bf(float f) {
    unsigned u = __builtin_bit_cast(unsigned, f);
    u = (u + 0x7fffu + ((u >> 16) & 1u)) >> 16;
    return (short)u;
}
static __device__ __forceinline__ float bf2f(short s) {
    unsigned u = ((unsigned)(unsigned short)s) << 16;
    return __builtin_bit_cast(float, u);
}
static __device__ __forceinline__ uchar f2fp8(float f) {
    return (uchar)(__builtin_amdgcn_cvt_pk_fp8_f32(f, 0.f, 0, false) & 0xff);
}

// async global->LDS, 16B per lane; lds dest = wave-uniform base + lane*16
static __device__ __forceinline__ void gld16(const void* g, void* l) {
    __builtin_amdgcn_global_load_lds(
        (const __attribute__((address_space(1))) void*)(g),
        (__attribute__((address_space(3))) void*)(l),
        16, 0, 0);
}

// ---------------- K0 (merged prep): W_kvl^T->fp8, W_out^T->bf16, emb->fp8 ----------------
__global__ void prep(const float* __restrict__ Wkvl, uchar* __restrict__ Wt8,
                     const float* __restrict__ Wout, short* __restrict__ Wot,
                     const float* __restrict__ emb, int* __restrict__ emb8) {
    __shared__ float t[32][33];
    int bid = blockIdx.x, tid = threadIdx.x;
    if (bid < 768) {           // transpose_fp8: W_kvl [512][1536] -> Wt8 [1536][512]
        int c0 = (bid % 48) * 32, r0 = (bid / 48) * 32;
        int x = tid & 31, y = tid >> 5;
        for (int k = 0; k < 32; k += 8)
            t[y + k][x] = Wkvl[(long)(r0 + y + k) * 1536 + c0 + x];
        __syncthreads();
        for (int k = 0; k < 32; k += 8)
            Wt8[(long)(c0 + y + k) * 512 + r0 + x] = f2fp8(t[x][y + k]);
    } else if (bid < 1024) {   // transpose_bf16: W_out [512][512] -> Wot [512][512]
        int bb = bid - 768;
        int c0 = (bb & 15) * 32, r0 = (bb >> 4) * 32;
        int x = tid & 31, y = tid >> 5;
        for (int k = 0; k < 32; k += 8)
            t[y + k][x] = Wout[(long)(r0 + y + k) * 512 + c0 + x];
        __syncthreads();
        for (int k = 0; k < 32; k += 8)
            Wot[(long)(c0 + y + k) * 512 + r0 + x] = f2bf(t[x][y + k]);
    } else {                   // cvt_fp8: emb f32 -> fp8, 8 elems/thread
        int i = (bid - 1024) * 256 + tid;
        long o = (long)i * 8;
        v4f a = *(const v4f*)(emb + o);
        v4f b = *(const v4f*)(emb + o + 4);
        int lo = __builtin_amdgcn_cvt_pk_fp8_f32(a.x, a.y, 0, false);
        lo = __builtin_amdgcn_cvt_pk_fp8_f32(a.z, a.w, lo, true);
        int hi = __builtin_amdgcn_cvt_pk_fp8_f32(b.x, b.y, 0, false);
        hi = __builtin_amdgcn_cvt_pk_fp8_f32(b.z, b.w, hi, true);
        int2 r; r.x = lo; r.y = hi;
        *(int2*)(emb8 + i * 2) = r;
    }
}

// ---------------- K1: kvl8[64000][1536] = emb8 @ Wt8  (MX-fp8, unit scales) ----------------
// 128x128 tile, BK=128, 8 waves (2m x 4n, wave tile 64x32), double-buffered 64KiB LDS.
// Same proven counted-vmcnt schedule as R8, repartitioned for 16 waves/CU:
// VGPR ~110 (acc 32 + frags 48) -> 2 blocks x 8 waves resident (vs R8's 8 waves/CU).
// Per-wave ledger: stage=4 gld16/tile; prologue vmcnt(4); boundaries vmcnt(4)/(0).
__global__ __launch_bounds__(512) void gemm_kvl(const uchar* __restrict__ emb8,
                                                const uchar* __restrict__ Wt8,
                                                uchar* __restrict__ kvl8) {
    extern __shared__ __align__(16) uchar smem[];
    uchar* As0 = smem;           // 2 x 16384 (A: 128 rows x 128B)
    uchar* Bs0 = smem + 32768;   // 2 x 16384 (B: 128 rows x 128B)
    int tid = threadIdx.x;
    // XCD swizzle: nwg=6000, divisible by 8 -> simple bijective form
    int id = blockIdx.x;
    int wgid = (id & 7) * 750 + (id >> 3);
    int m_idx = wgid / 12, n_idx = wgid - m_idx * 12;
    int m0 = m_idx * 128, n0 = n_idx * 128;
    int wid = tid >> 6, lane = tid & 63, quad = lane >> 4, l16 = lane & 15;
    int wm = wid & 1, wn = wid >> 1;   // wave tile: 64(m) x 32(n); wn in 0..3
    const uchar* Ag = emb8 + (long)m0 * 512;
    const uchar* Bg = Wt8 + (long)n0 * 512;
    int rsub = lane >> 3;
    int kc = ((lane & 7) ^ rsub) * 16;   // pre-swizzled global source chunk

    v4f acc[4][2] = {};

    // stage tile (A 16KB + B 16KB): 8 waves x 4 gld16 (2 A + 2 B)
    auto stageAB = [&](int bi, int kk) {
        #pragma unroll
        for (int p = 0; p < 2; ++p) {
            int rl = wid * 16 + p * 8;
            gld16(Ag + (long)(rl + rsub) * 512 + kk + kc, As0 + bi * 16384 + rl * 128);
        }
        #pragma unroll
        for (int p = 0; p < 2; ++p) {
            int rl = wid * 16 + p * 8;
            gld16(Bg + (long)(rl + rsub) * 512 + kk + kc, Bs0 + bi * 16384 + rl * 128);
        }
    };
    // swizzled 32B fragment load (2x ds_read_b128)
    auto ldfrag = [&](const uchar* base, int row) -> v8i {
        int c0 = (quad * 2) ^ (row & 7);
        v4i lo = *(const v4i*)(base + row * 128 + c0 * 16);
        v4i hi = *(const v4i*)(base + row * 128 + (c0 ^ 1) * 16);
        return __builtin_shufflevector(lo, hi, 0, 1, 2, 3, 4, 5, 6, 7);
    };

    // prologue: stage K-tiles 0 and 1; counted wait -> tile-1 loads stay in flight
    stageAB(0, 0);
    stageAB(1, 128);
    asm volatile("s_waitcnt vmcnt(4)" ::: "memory");   // tile-0's 4 loads done
    __builtin_amdgcn_s_barrier();
    __builtin_amdgcn_sched_barrier(0);

    v8i af[4], bf[2];
    #pragma unroll
    for (int t = 0; t < 4; ++t) {
        int cur = t & 1;
        const uchar* ab = As0 + cur * 16384;
        const uchar* bb = Bs0 + cur * 16384;
        // ---- read burst: all frags of this tile ----
        #pragma unroll
        for (int i = 0; i < 4; ++i) af[i] = ldfrag(ab, wm * 64 + i * 16 + l16);
        #pragma unroll
        for (int j = 0; j < 2; ++j) bf[j] = ldfrag(bb, wn * 32 + j * 16 + l16);
        // ---- MFMA half 1: acc[i][0] ----
        __builtin_amdgcn_s_setprio(1);
        #pragma unroll
        for (int i = 0; i < 4; ++i)
            acc[i][0] = __builtin_amdgcn_mfma_scale_f32_16x16x128_f8f6f4(
                af[i], bf[0], acc[i][0], 0, 0, 0, 0x7f7f7f7f, 0, 0x7f7f7f7f);
        __builtin_amdgcn_s_setprio(0);
        // ---- all ds_reads retired -> safe to overwrite cur buf ----
        asm volatile("s_waitcnt lgkmcnt(0)" ::: "memory");
        __builtin_amdgcn_s_barrier();
        if (t < 2) stageAB(cur, (t + 2) * 128);   // stage tile t+2 into cur
        // ---- MFMA half 2: acc[i][1] (pure reg; hides stage issue) ----
        __builtin_amdgcn_s_setprio(1);
        #pragma unroll
        for (int i = 0; i < 4; ++i)
            acc[i][1] = __builtin_amdgcn_mfma_scale_f32_16x16x128_f8f6f4(
                af[i], bf[1], acc[i][1], 0, 0, 0, 0x7f7f7f7f, 0, 0x7f7f7f7f);
        __builtin_amdgcn_s_setprio(0);
        // ---- tile boundary: counted wait (t+1 ready; t+2 stays in flight) ----
        if (t < 3) {
            if (t < 2) asm volatile("s_waitcnt vmcnt(4)" ::: "memory");
            else       asm volatile("s_waitcnt vmcnt(0)" ::: "memory");
            __builtin_amdgcn_s_barrier();
            __builtin_amdgcn_sched_barrier(0);
        }
    }
    __syncthreads();  // epilogue guard

    // epilogue: wave-private 16x32 bf16 staging (stride 40 shorts) -> 8B fp8 stores
    short* rp = (short*)smem;
    short* r = rp + wid * (16 * 40);
    int nw = n0 + wn * 32;
    #pragma unroll
    for (int i = 0; i < 4; ++i) {
        #pragma unroll
        for (int jj = 0; jj < 2; ++jj)
            #pragma unroll
            for (int rr = 0; rr < 4; ++rr)
                r[(quad * 4 + rr) * 40 + jj * 16 + l16] = f2bf(acc[i][jj][rr]);
        {
            int rowl = lane >> 2;           // 16 rows
            int colc = (lane & 3) * 8;      // 4 chunks of 8 shorts
            v8s val = *(const v8s*)(r + rowl * 40 + colc);
            int lo = __builtin_amdgcn_cvt_pk_fp8_f32(bf2f(val[0]), bf2f(val[1]), 0, false);
            lo = __builtin_amdgcn_cvt_pk_fp8_f32(bf2f(val[2]), bf2f(val[3]), lo, true);
            int hi = __builtin_amdgcn_cvt_pk_fp8_f32(bf2f(val[4]), bf2f(val[5]), 0, false);
            hi = __builtin_amdgcn_cvt_pk_fp8_f32(bf2f(val[6]), bf2f(val[7]), hi, true);
            int2 st; st.x = lo; st.y = hi;
            *(int2*)(kvl8 + (long)(m0 + wm * 64 + i * 16 + rowl) * 1536 +
                     nw + colc) = st;
        }
    }
}

// ---------------- K2: pack K,V into MFMA-fragment-ready layouts (R9-proven) ----------------
__global__ void pack_kv(const uchar* __restrict__ kvl8, uchar* __restrict__ Kf,
                        uchar* __restrict__ Vf) {
    int bh = blockIdx.x, b = bh >> 3, h = bh & 7;
    int g = blockIdx.y;            // node group: nodes g*64 .. g*64+63
    __shared__ uchar Kl[64][72];
    __shared__ uchar VT[64][72];
    int tid = threadIdx.x;
    int node_l = tid >> 2, chunk = (tid & 3) * 16;
    int gn = g * 64 + node_l;
    int ncl = gn < NN ? gn : NN - 1;   // clamp: padded nodes masked downstream
    const uchar* rowp = kvl8 + ((long)b * NN + ncl) * 1536 + h * 64;
    *(v4i*)&Kl[node_l][chunk] = *(const v4i*)(rowp + chunk);
    {
        const uchar* vp = rowp + 512 + chunk;
        ulong_t v0 = *(const ulong_t*)(vp);
        ulong_t v1 = *(const ulong_t*)(vp + 8);
        uchar* b0p = (uchar*)&v0; uchar* b1p = (uchar*)&v1;
        #pragma unroll
        for (int j = 0; j < 8; ++j) VT[chunk + j][node_l] = b0p[j];
        #pragma unroll
        for (int j = 0; j < 8; ++j) VT[chunk + 8 + j][node_l] = b1p[j];
    }
    __syncthreads();
    int wid = tid >> 6, lane = tid & 63, l16 = lane & 15, quad = lane >> 4;
    #pragma unroll
    for (int ks = 0; ks < 2; ++ks) {
        ulong_t frag = *(const ulong_t*)&Kl[wid * 16 + l16][ks * 32 + quad * 8];
        *(ulong_t*)(Kf + (((long)bh * 64 + g * 4 + wid) * 2 + ks) * 512 + lane * 8) = frag;
    }
    #pragma unroll
    for (int sub = 0; sub < 2; ++sub) {
        ulong_t frag = *(const ulong_t*)&VT[wid * 16 + l16][sub * 32 + quad * 8];
        *(ulong_t*)(Vf + (((long)bh * 4 + wid) * 32 + g * 2 + sub) * 512 + lane * 8) = frag;
    }
}

// ---------------- K3: fused QK^T -> masked softmax -> PV (fp8, 512 threads) ----------------
#define CST 1036  // cmp row stride (shorts): 518 words/row -> conflict-free frag reads
__global__ __launch_bounds__(512) void attn_fused(const float* __restrict__ q,
                                                  const uchar* __restrict__ Kf,
                                                  const uchar* __restrict__ Vf,
                                                  const int* __restrict__ mask,
                                                  float* __restrict__ heads) {
    int b = blockIdx.x, h = blockIdx.y;
    __shared__ __align__(16) uchar qs[32 * 72];
    __shared__ __align__(16) short cmp[SS * CST];
    int tid = threadIdx.x, wid = tid >> 6, lane = tid & 63, quad = lane >> 4, l16 = lane & 15;
    for (int i = tid; i < 32 * 64; i += 512) {
        int row = i >> 6, col = i & 63;
        float v = (row < SS) ? q[((long)b * SS + row) * DD + h * 64 + col] : 0.f;
        qs[row * 72 + col] = f2fp8(v);
    }
    __syncthreads();
    long af[2][2];
    #pragma unroll
    for (int mt = 0; mt < 2; ++mt)
        #pragma unroll
        for (int ks = 0; ks < 2; ++ks)
            af[mt][ks] = *(const long*)(qs + (mt * 16 + l16) * 72 + ks * 32 + quad * 8);
    const uchar* kfb = Kf + ((long)(b * HH + h) * 64) * 1024;
    for (int t = 0; t < 8; ++t) {
        int nt = wid * 8 + t;
        long b0 = *(const long*)(kfb + (long)nt * 1024 + lane * 8);
        long b1 = *(const long*)(kfb + (long)nt * 1024 + 512 + lane * 8);
        #pragma unroll
        for (int mt = 0; mt < 2; ++mt) {
            v4f a = {};
            a = __builtin_amdgcn_mfma_f32_16x16x32_fp8_fp8(af[mt][0], b0, a, 0, 0, 0);
            a = __builtin_amdgcn_mfma_f32_16x16x32_fp8_fp8(af[mt][1], b1, a, 0, 0, 0);
            #pragma unroll
            for (int r = 0; r < 4; ++r) {
                int s = mt * 16 + quad * 4 + r;
                if (s < SS) cmp[s * CST + nt * 16 + l16] = f2bf(a[r] * 0.125f);
            }
        }
    }
    __syncthreads();
    for (int s = wid; s < SS; s += 8) {
        const int* mr = mask + ((long)b * SS + s) * NN;
        float x[16];
        float mx = NEGV;
        #pragma unroll
        for (int i = 0; i < 16; ++i) {
            int n = lane + 64 * i;
            float v = bf2f(cmp[s * CST + n]);
            bool feas = (n < NN) && (mr[n < NN ? n : 0] != 0);
            x[i] = feas ? v : NEGV;
            mx = fmaxf(mx, x[i]);
        }
        for (int off = 32; off; off >>= 1) mx = fmaxf(mx, __shfl_xor(mx, off));
        float sum = 0.f;
        #pragma unroll
        for (int i = 0; i < 16; ++i) { x[i] = __expf(x[i] - mx); sum += x[i]; }
        for (int off = 32; off; off >>= 1) sum += __shfl_xor(sum, off);
        float inv = 1.0f / sum;
        uchar* pr = (uchar*)cmp + (long)s * (CST * 2);
        #pragma unroll
        for (int i = 0; i < 16; ++i) pr[lane + 64 * i] = f2fp8(x[i] * inv);
    }
    __syncthreads();
    int mt = wid & 1, dt = wid >> 1;  // dt in 0..3
    int srow = mt * 16 + l16; if (srow > SS - 1) srow = SS - 1;
    const uchar* ap = (const uchar*)cmp + (long)srow * (CST * 2) + quad * 8;
    const uchar* vfb = Vf + (((long)(b * HH + h) * 4 + dt) * 32) * 512;
    v4f a0 = {}, a1 = {}, a2 = {}, a3 = {};
    for (int k0s = 0; k0s < 32; k0s += 4) {
        a0 = __builtin_amdgcn_mfma_f32_16x16x32_fp8_fp8(
            *(const long*)(ap + k0s * 32),
            *(const long*)(vfb + (long)k0s * 512 + lane * 8), a0, 0, 0, 0);
        a1 = __builtin_amdgcn_mfma_f32_16x16x32_fp8_fp8(
            *(const long*)(ap + (k0s + 1) * 32),
            *(const long*)(vfb + (long)(k0s + 1) * 512 + lane * 8), a1, 0, 0, 0);
        a2 = __builtin_amdgcn_mfma_f32_16x16x32_fp8_fp8(
            *(const long*)(ap + (k0s + 2) * 32),
            *(const long*)(vfb + (long)(k0s + 2) * 512 + lane * 8), a2, 0, 0, 0);
        a3 = __builtin_amdgcn_mfma_f32_16x16x32_fp8_fp8(
            *(const long*)(ap + (k0s + 3) * 32),
            *(const long*)(vfb + (long)(k0s + 3) * 512 + lane * 8), a3, 0, 0, 0);
    }
    v4f accv = (a0 + a1) + (a2 + a3);
    #pragma unroll
    for (int r = 0; r < 4; ++r) {
        int s = mt * 16 + quad * 4 + r;
        if (s < SS)
            heads[((long)b * SS + s) * DD + h * 64 + dt * 16 + l16] = accv[r];
    }
}

// ---------------- K4: glimpse[1280][512] = heads @ W_out (bf16) ----------------
__global__ __launch_bounds__(256) void out_proj(const float* __restrict__ heads,
                                                const short* __restrict__ Wot,
                                                float* __restrict__ glimpse) {
    __shared__ __align__(16) short As[64 * 40], Bs[64 * 40];
    int tid = threadIdx.x;
    int m0 = blockIdx.x * 64, n0 = blockIdx.y * 64;
    int wid = tid >> 6, lane = tid & 63, quad = lane >> 4, l16 = lane & 15;
    int wm = wid & 1, wn = wid >> 1;
    int arow = tid >> 3, akol = (tid & 7) * 4;
    int brow = tid >> 2, bkol = (tid & 3) * 8;
    v4f acc[2][2] = {};
    for (int kk = 0; kk < 512; kk += 32) {
        #pragma unroll
        for (int p = 0; p < 2; ++p) {
            int r = arow + p * 32;
            v4f a = *(const v4f*)(heads + (long)(m0 + r) * 512 + kk + akol);
            short4 s4;
            s4.x = f2bf(a.x); s4.y = f2bf(a.y); s4.z = f2bf(a.z); s4.w = f2bf(a.w);
            *(short4*)(As + r * 40 + akol) = s4;
        }
        *(uint4*)(Bs + brow * 40 + bkol) =
            *(const uint4*)(Wot + (long)(n0 + brow) * 512 + kk + bkol);
        __syncthreads();
        #pragma unroll
        for (int i = 0; i < 2; ++i) {
            v8s af = *(const v8s*)(As + (wm * 32 + i * 16 + l16) * 40 + quad * 8);
            #pragma unroll
            for (int j = 0; j < 2; ++j) {
                v8s bf = *(const v8s*)(Bs + (wn * 32 + j * 16 + l16) * 40 + quad * 8);
                acc[i][j] = __builtin_amdgcn_mfma_f32_16x16x32_bf16(af, bf, acc[i][j], 0, 0, 0);
            }
        }
        __syncthreads();
    }
    #pragma unroll
    for (int i = 0; i < 2; ++i)
        #pragma unroll
        for (int j = 0; j < 2; ++j)
            #pragma unroll
            for (int r = 0; r < 4; ++r)
                glimpse[(long)(m0 + wm * 32 + i * 16 + quad * 4 + r) * 512 +
                        n0 + wn * 32 + j * 16 + l16] = acc[i][j][r];
}

// ---------------- K5: logits = (glimpse . logit_k^T)/sqrt(512)  (fp8) ----------------
__global__ __launch_bounds__(256) void ptr_logits(const float* __restrict__ glimpse,
                                                  const uchar* __restrict__ kvl8,
                                                  float* __restrict__ logits) {
    int b = blockIdx.x, g = blockIdx.y;  // g in 0..15, one n-tile per wave
    __shared__ __align__(16) uchar Gs[32 * 520];
    int tid = threadIdx.x;
    #pragma unroll
    for (int it = 0; it < 16; ++it) {
        int e = it * 1024 + tid * 4;
        int row = e >> 9, col = e & 511;
        int pk = 0;
        if (row < SS) {
            v4f a = *(const v4f*)(glimpse + ((long)b * SS + row) * 512 + col);
            pk = __builtin_amdgcn_cvt_pk_fp8_f32(a.x, a.y, 0, false);
            pk = __builtin_amdgcn_cvt_pk_fp8_f32(a.z, a.w, pk, true);
        }
        *(int*)(Gs + row * 520 + col) = pk;
    }
    __syncthreads();
    int wid = tid >> 6, lane = tid & 63, quad = lane >> 4, l16 = lane & 15;
    const float scale = 0.04419417382415922f;  // 1/sqrt(512)
    int nt = g * 4 + wid;
    int n = nt * 16 + l16;
    int ncl = n < NN ? n : NN - 1;
    const uchar* kp = kvl8 + ((long)b * NN + ncl) * 1536 + 1024 + quad * 8;
    v4f acc[2] = {};
    for (int k = 0; k < 16; ++k) {
        long bfr = *(const long*)(kp + k * 32);
        #pragma unroll
        for (int m = 0; m < 2; ++m) {
            long afr = *(const long*)(Gs + (m * 16 + l16) * 520 + k * 32 + quad * 8);
            acc[m] = __builtin_amdgcn_mfma_f32_16x16x32_fp8_fp8(afr, bfr, acc[m], 0, 0, 0);
        }
    }
    #pragma unroll
    for (int m = 0; m < 2; ++m)
        #pragma unroll
        for (int r = 0; r < 4; ++r) {
            int s = m * 16 + quad * 4 + r;
            if (s < SS)
                logits[((long)b * SS + s) * NP + nt * 16 + l16] = acc[m][r] * scale;
        }
}

// ---------------- K6: tanh clip + mask + log_softmax + (s b) transpose ----------------
__global__ __launch_bounds__(256) void logsoftmax_out(const float* __restrict__ logits,
                                                      const int* __restrict__ mask,
                                                      float* __restrict__ out) {
    int row = blockIdx.x;  // b*20 + s
    int b = row / SS, s = row % SS;
    int tid = threadIdx.x;
    __shared__ float red[8];
    int n0 = tid * 4;
    v4f v = *(const v4f*)(logits + (long)row * NP + n0);
    const int* mr = mask + (long)row * NN;
    float x[4];
    float mx = NEGV;
    #pragma unroll
    for (int j = 0; j < 4; ++j) {
        int n = n0 + j;
        float t = 10.f * tanhf(v[j]);
        bool feas = (n < NN) && (mr[n < NN ? n : 0] != 0);
        x[j] = feas ? t : NEGV;
        mx = fmaxf(mx, x[j]);
    }
    for (int off = 32; off; off >>= 1) mx = fmaxf(mx, __shfl_xor(mx, off));
    int wid = tid >> 6, lane = tid & 63;
    if (lane == 0) red[wid] = mx;
    __syncthreads();
    mx = fmaxf(fmaxf(red[0], red[1]), fmaxf(red[2], red[3]));
    float sum = 0.f;
    #pragma unroll
    for (int j = 0; j < 4; ++j) sum += __expf(x[j] - mx);
    for (int off = 32; off; off >>= 1) sum += __shfl_xor(sum, off);
    __syncthreads();
    if (lane == 0) red[4 + wid] = sum;
    __syncthreads();
    sum = red[4] + red[5] + red[6] + red[7];
    float lse = mx + __logf(sum);
    float* orow = out + ((long)s * BB + b) * NN;
    #pragma unroll
    for (int j = 0; j < 4; ++j) {
        int n = n0 + j;
        if (n < NN) orow[n] = x[j] - lse;
    }
}

extern "C" void kernel_launch(void* const* d_in, const int* in_sizes, int n_in,
                              void* d_out, int out_size, void* d_ws, size_t ws_size,
                              hipStream_t stream) {
    const float* emb  = (const float*)d_in[0];
    const float* q    = (const float*)d_in[1];
    const int*   mask = (const int*)d_in[2];
    const float* Wkvl = (const float*)d_in[3];
    const float* Wout = (const float*)d_in[4];
    float* out = (float*)d_out;

    char* ws = (char*)d_ws;
    uchar* kvl8    = (uchar*)ws; ws += (size_t)64000 * 1536;
    uchar* Vf      = (uchar*)ws; ws += (size_t)512 * 64 * NP;      // 33.55 MB
    uchar* Wt8     = (uchar*)ws; ws += (size_t)1536 * 512;
    uchar* emb8    = (uchar*)ws; ws += (size_t)64000 * 512;
    short* Wot     = (short*)ws; ws += (size_t)512 * 512 * 2;
    float* heads   = (float*)ws; ws += (size_t)BB * SS * DD * 4;
    float* glimpse = (float*)ws; ws += (size_t)BB * SS * DD * 4;
    float* logits  = (float*)ws; ws += (size_t)BB * SS * NP * 4;

    // Kf overlays Wt8+emb8 (both dead after gemm_kvl):
    // Kf = 512bh*64nt*2ks*512B = 33,554,432B == Wt8(786,432)+emb8(32,768,000) exactly.
    uchar* Kf = Wt8;

    static int s_attr_done = 0;
    if (!s_attr_done) {
        hipFuncSetAttribute(reinterpret_cast<const void*>(gemm_kvl),
                            hipFuncAttributeMaxDynamicSharedMemorySize, 65536);
        s_attr_done = 1;
    }

    prep<<<dim3(1024 + 16000), 256, 0, stream>>>(Wkvl, Wt8, Wout, Wot, emb, (int*)emb8);
    gemm_kvl<<<dim3(6000), 512, 65536, stream>>>(emb8, Wt8, kvl8);
    pack_kv<<<dim3(512, 16), 256, 0, stream>>>(kvl8, Kf, Vf);
    attn_fused<<<dim3(BB, HH), 512, 0, stream>>>(q, Kf, Vf, mask, heads);
    out_proj<<<dim3(20, 8), 256, 0, stream>>>(heads, Wot, glimpse);
    ptr_logits<<<dim3(BB, 16), 256, 0, stream>>>(glimpse, kvl8, logits);
    logsoftmax_out<<<dim3(BB * SS), 256, 0, stream>>>(logits, mask, out);
}

// Round 14
// 335.463 us; speedup vs baseline: 1.1155x; 1.0352x over previous
//
#include <hip/hip_runtime.h>

#define BB 64
#define NN 1000
#define NP 1024
#define DD 512
#define HH 8
#define SS 20
#define NEGV -1e9f

typedef float v4f __attribute__((ext_vector_type(4)));
typedef short v8s __attribute__((ext_vector_type(8)));
typedef int   v8i __attribute__((ext_vector_type(8)));
typedef int   v4i __attribute__((ext_vector_type(4)));
typedef unsigned char uchar;
typedef unsigned long long ulong_t;

static __device__ __forceinline__ short f2bf(float f) {
    unsigned u = __builtin_bit_cast(unsigned, f);
    u = (u + 0x7fffu + ((u >> 16) & 1u)) >> 16;
    return (short)u;
}
static __device__ __forceinline__ float bf2f(short s) {
    unsigned u = ((unsigned)(unsigned short)s) << 16;
    return __builtin_bit_cast(float, u);
}
static __device__ __forceinline__ uchar f2fp8(float f) {
    return (uchar)(__builtin_amdgcn_cvt_pk_fp8_f32(f, 0.f, 0, false) & 0xff);
}

// async global->LDS, 16B per lane; lds dest = wave-uniform base + lane*16
static __device__ __forceinline__ void gld16(const void* g, void* l) {
    __builtin_amdgcn_global_load_lds(
        (const __attribute__((address_space(1))) void*)(g),
        (__attribute__((address_space(3))) void*)(l),
        16, 0, 0);
}

// ---------------- K0 (merged prep): W_kvl^T->fp8, W_out^T->bf16, emb->fp8 ----------------
__global__ void prep(const float* __restrict__ Wkvl, uchar* __restrict__ Wt8,
                     const float* __restrict__ Wout, short* __restrict__ Wot,
                     const float* __restrict__ emb, int* __restrict__ emb8) {
    __shared__ float t[32][33];
    int bid = blockIdx.x, tid = threadIdx.x;
    if (bid < 768) {           // transpose_fp8: W_kvl [512][1536] -> Wt8 [1536][512]
        int c0 = (bid % 48) * 32, r0 = (bid / 48) * 32;
        int x = tid & 31, y = tid >> 5;
        for (int k = 0; k < 32; k += 8)
            t[y + k][x] = Wkvl[(long)(r0 + y + k) * 1536 + c0 + x];
        __syncthreads();
        for (int k = 0; k < 32; k += 8)
            Wt8[(long)(c0 + y + k) * 512 + r0 + x] = f2fp8(t[x][y + k]);
    } else if (bid < 1024) {   // transpose_bf16: W_out [512][512] -> Wot [512][512]
        int bb = bid - 768;
        int c0 = (bb & 15) * 32, r0 = (bb >> 4) * 32;
        int x = tid & 31, y = tid >> 5;
        for (int k = 0; k < 32; k += 8)
            t[y + k][x] = Wout[(long)(r0 + y + k) * 512 + c0 + x];
        __syncthreads();
        for (int k = 0; k < 32; k += 8)
            Wot[(long)(c0 + y + k) * 512 + r0 + x] = f2bf(t[x][y + k]);
    } else {                   // cvt_fp8: emb f32 -> fp8, 8 elems/thread
        int i = (bid - 1024) * 256 + tid;
        long o = (long)i * 8;
        v4f a = *(const v4f*)(emb + o);
        v4f b = *(const v4f*)(emb + o + 4);
        int lo = __builtin_amdgcn_cvt_pk_fp8_f32(a.x, a.y, 0, false);
        lo = __builtin_amdgcn_cvt_pk_fp8_f32(a.z, a.w, lo, true);
        int hi = __builtin_amdgcn_cvt_pk_fp8_f32(b.x, b.y, 0, false);
        hi = __builtin_amdgcn_cvt_pk_fp8_f32(b.z, b.w, hi, true);
        int2 r; r.x = lo; r.y = hi;
        *(int2*)(emb8 + i * 2) = r;
    }
}

// ---------------- K1: kvl8[64000][1536] = emb8 @ Wt8  (MX-fp8, unit scales) ----------------
// R13-proven: 128x128 tile, BK=128, 8 waves (2m x 4n), 64KiB dbuf LDS, 16 waves/CU.
__global__ __launch_bounds__(512) void gemm_kvl(const uchar* __restrict__ emb8,
                                                const uchar* __restrict__ Wt8,
                                                uchar* __restrict__ kvl8) {
    extern __shared__ __align__(16) uchar smem[];
    uchar* As0 = smem;           // 2 x 16384 (A: 128 rows x 128B)
    uchar* Bs0 = smem + 32768;   // 2 x 16384 (B: 128 rows x 128B)
    int tid = threadIdx.x;
    // XCD swizzle: nwg=6000, divisible by 8 -> simple bijective form
    int id = blockIdx.x;
    int wgid = (id & 7) * 750 + (id >> 3);
    int m_idx = wgid / 12, n_idx = wgid - m_idx * 12;
    int m0 = m_idx * 128, n0 = n_idx * 128;
    int wid = tid >> 6, lane = tid & 63, quad = lane >> 4, l16 = lane & 15;
    int wm = wid & 1, wn = wid >> 1;   // wave tile: 64(m) x 32(n); wn in 0..3
    const uchar* Ag = emb8 + (long)m0 * 512;
    const uchar* Bg = Wt8 + (long)n0 * 512;
    int rsub = lane >> 3;
    int kc = ((lane & 7) ^ rsub) * 16;   // pre-swizzled global source chunk

    v4f acc[4][2] = {};

    auto stageAB = [&](int bi, int kk) {
        #pragma unroll
        for (int p = 0; p < 2; ++p) {
            int rl = wid * 16 + p * 8;
            gld16(Ag + (long)(rl + rsub) * 512 + kk + kc, As0 + bi * 16384 + rl * 128);
        }
        #pragma unroll
        for (int p = 0; p < 2; ++p) {
            int rl = wid * 16 + p * 8;
            gld16(Bg + (long)(rl + rsub) * 512 + kk + kc, Bs0 + bi * 16384 + rl * 128);
        }
    };
    auto ldfrag = [&](const uchar* base, int row) -> v8i {
        int c0 = (quad * 2) ^ (row & 7);
        v4i lo = *(const v4i*)(base + row * 128 + c0 * 16);
        v4i hi = *(const v4i*)(base + row * 128 + (c0 ^ 1) * 16);
        return __builtin_shufflevector(lo, hi, 0, 1, 2, 3, 4, 5, 6, 7);
    };

    stageAB(0, 0);
    stageAB(1, 128);
    asm volatile("s_waitcnt vmcnt(4)" ::: "memory");   // tile-0's 4 loads done
    __builtin_amdgcn_s_barrier();
    __builtin_amdgcn_sched_barrier(0);

    v8i af[4], bf[2];
    #pragma unroll
    for (int t = 0; t < 4; ++t) {
        int cur = t & 1;
        const uchar* ab = As0 + cur * 16384;
        const uchar* bb = Bs0 + cur * 16384;
        #pragma unroll
        for (int i = 0; i < 4; ++i) af[i] = ldfrag(ab, wm * 64 + i * 16 + l16);
        #pragma unroll
        for (int j = 0; j < 2; ++j) bf[j] = ldfrag(bb, wn * 32 + j * 16 + l16);
        __builtin_amdgcn_s_setprio(1);
        #pragma unroll
        for (int i = 0; i < 4; ++i)
            acc[i][0] = __builtin_amdgcn_mfma_scale_f32_16x16x128_f8f6f4(
                af[i], bf[0], acc[i][0], 0, 0, 0, 0x7f7f7f7f, 0, 0x7f7f7f7f);
        __builtin_amdgcn_s_setprio(0);
        asm volatile("s_waitcnt lgkmcnt(0)" ::: "memory");
        __builtin_amdgcn_s_barrier();
        if (t < 2) stageAB(cur, (t + 2) * 128);
        __builtin_amdgcn_s_setprio(1);
        #pragma unroll
        for (int i = 0; i < 4; ++i)
            acc[i][1] = __builtin_amdgcn_mfma_scale_f32_16x16x128_f8f6f4(
                af[i], bf[1], acc[i][1], 0, 0, 0, 0x7f7f7f7f, 0, 0x7f7f7f7f);
        __builtin_amdgcn_s_setprio(0);
        if (t < 3) {
            if (t < 2) asm volatile("s_waitcnt vmcnt(4)" ::: "memory");
            else       asm volatile("s_waitcnt vmcnt(0)" ::: "memory");
            __builtin_amdgcn_s_barrier();
            __builtin_amdgcn_sched_barrier(0);
        }
    }
    __syncthreads();  // epilogue guard

    // epilogue: wave-private 16x32 bf16 staging (stride 40 shorts) -> 8B fp8 stores
    short* rp = (short*)smem;
    short* r = rp + wid * (16 * 40);
    int nw = n0 + wn * 32;
    #pragma unroll
    for (int i = 0; i < 4; ++i) {
        #pragma unroll
        for (int jj = 0; jj < 2; ++jj)
            #pragma unroll
            for (int rr = 0; rr < 4; ++rr)
                r[(quad * 4 + rr) * 40 + jj * 16 + l16] = f2bf(acc[i][jj][rr]);
        {
            int rowl = lane >> 2;           // 16 rows
            int colc = (lane & 3) * 8;      // 4 chunks of 8 shorts
            v8s val = *(const v8s*)(r + rowl * 40 + colc);
            int lo = __builtin_amdgcn_cvt_pk_fp8_f32(bf2f(val[0]), bf2f(val[1]), 0, false);
            lo = __builtin_amdgcn_cvt_pk_fp8_f32(bf2f(val[2]), bf2f(val[3]), lo, true);
            int hi = __builtin_amdgcn_cvt_pk_fp8_f32(bf2f(val[4]), bf2f(val[5]), 0, false);
            hi = __builtin_amdgcn_cvt_pk_fp8_f32(bf2f(val[6]), bf2f(val[7]), hi, true);
            int2 st; st.x = lo; st.y = hi;
            *(int2*)(kvl8 + (long)(m0 + wm * 64 + i * 16 + rowl) * 1536 +
                     nw + colc) = st;
        }
    }
}

// ---------------- K3: fused V-pack -> QK^T -> masked softmax -> PV ----------------
// pack_kv kernel DELETED: each (b,h) block builds its own V-fragment region in LDS
// (identical indexing to the proven pack_kv VT->frag path; producer==consumer, no
// fences). K read scattered from kvl8 (R8-proven neutral vs packed).
// Dynamic LDS: qs 2304 | cmp 41440 (shorts; first 9216B reused as VT scratch) |
// VfL 65536 (flat Vf-slice layout) = 109,280 B -> 1 block/CU.
#define CST 1036  // cmp row stride (shorts): 518 words/row -> conflict-free frag reads
__global__ __launch_bounds__(512) void attn_fused(const float* __restrict__ q,
                                                  const uchar* __restrict__ kvl8,
                                                  const int* __restrict__ mask,
                                                  float* __restrict__ heads) {
    extern __shared__ __align__(16) uchar asm_[];
    uchar* qs = asm_;                       // 32*72 = 2304
    short* cmp = (short*)(asm_ + 2304);     // 20*1036 shorts = 41440 B
    uchar* vscr = (uchar*)cmp;              // VT scratch: 2 x [64][72] = 9216 B (pre-QK^T)
    uchar* VfL = asm_ + 43744;              // 4dt*32k0s*512 = 65536 B
    int b = blockIdx.x, h = blockIdx.y;
    int tid = threadIdx.x, wid = tid >> 6, lane = tid & 63, quad = lane >> 4, l16 = lane & 15;

    // ---- qs staging (visibility covered by the V-build syncs below) ----
    for (int i = tid; i < 32 * 64; i += 512) {
        int row = i >> 6, col = i & 63;
        float v = (row < SS) ? q[((long)b * SS + row) * DD + h * 64 + col] : 0.f;
        qs[row * 72 + col] = f2fp8(v);
    }

    // ---- V build: 16 node-groups, 2 per iteration (proven pack_kv logic) ----
    {
        int gsub = tid >> 8;                // 0 or 1
        int t2 = tid & 255;
        int node_l = t2 >> 2, chunk = (t2 & 3) * 16;
        int wid2 = t2 >> 6, lane2 = t2 & 63, l162 = lane2 & 15, quad2 = lane2 >> 4;
        uchar* VT = vscr + gsub * 4608;     // [64][72]
        for (int gg = 0; gg < 8; ++gg) {
            int g = gg * 2 + gsub;
            int gn = g * 64 + node_l;
            int ncl = gn < NN ? gn : NN - 1;   // clamp: pad nodes masked by P=0 in PV
            const uchar* vp = kvl8 + ((long)b * NN + ncl) * 1536 + 512 + h * 64 + chunk;
            ulong_t v0 = *(const ulong_t*)(vp);
            ulong_t v1 = *(const ulong_t*)(vp + 8);
            uchar* b0p = (uchar*)&v0; uchar* b1p = (uchar*)&v1;
            #pragma unroll
            for (int j = 0; j < 8; ++j) VT[(chunk + j) * 72 + node_l] = b0p[j];
            #pragma unroll
            for (int j = 0; j < 8; ++j) VT[(chunk + 8 + j) * 72 + node_l] = b1p[j];
            __syncthreads();
            #pragma unroll
            for (int sub = 0; sub < 2; ++sub) {
                ulong_t frag = *(const ulong_t*)&VT[(wid2 * 16 + l162) * 72 + sub * 32 + quad2 * 8];
                *(ulong_t*)(VfL + ((wid2 * 32) + (g * 2 + sub)) * 512 + lane2 * 8) = frag;
            }
            __syncthreads();
        }
    }

    // --- QK^T (fp8), /8 on f32 output; K scattered from kvl8 (R8-proven) ---
    long af[2][2];
    #pragma unroll
    for (int mt = 0; mt < 2; ++mt)
        #pragma unroll
        for (int ks = 0; ks < 2; ++ks)
            af[mt][ks] = *(const long*)(qs + (mt * 16 + l16) * 72 + ks * 32 + quad * 8);
    for (int t = 0; t < 8; ++t) {
        int nt = wid * 8 + t;
        int n = nt * 16 + l16;
        int nc = n < NN ? n : NN - 1;
        const uchar* kp = kvl8 + ((long)b * NN + nc) * 1536 + h * 64 + quad * 8;
        long b0 = *(const long*)kp;
        long b1 = *(const long*)(kp + 32);
        #pragma unroll
        for (int mt = 0; mt < 2; ++mt) {
            v4f a = {};
            a = __builtin_amdgcn_mfma_f32_16x16x32_fp8_fp8(af[mt][0], b0, a, 0, 0, 0);
            a = __builtin_amdgcn_mfma_f32_16x16x32_fp8_fp8(af[mt][1], b1, a, 0, 0, 0);
            #pragma unroll
            for (int r = 0; r < 4; ++r) {
                int s = mt * 16 + quad * 4 + r;
                if (s < SS) cmp[s * CST + nt * 16 + l16] = f2bf(a[r] * 0.125f);
            }
        }
    }
    __syncthreads();
    // --- masked softmax; P written as fp8 bytes in place ---
    for (int s = wid; s < SS; s += 8) {
        const int* mr = mask + ((long)b * SS + s) * NN;
        float x[16];
        float mx = NEGV;
        #pragma unroll
        for (int i = 0; i < 16; ++i) {
            int n = lane + 64 * i;
            float v = bf2f(cmp[s * CST + n]);
            bool feas = (n < NN) && (mr[n < NN ? n : 0] != 0);
            x[i] = feas ? v : NEGV;
            mx = fmaxf(mx, x[i]);
        }
        for (int off = 32; off; off >>= 1) mx = fmaxf(mx, __shfl_xor(mx, off));
        float sum = 0.f;
        #pragma unroll
        for (int i = 0; i < 16; ++i) { x[i] = __expf(x[i] - mx); sum += x[i]; }
        for (int off = 32; off; off >>= 1) sum += __shfl_xor(sum, off);
        float inv = 1.0f / sum;
        uchar* pr = (uchar*)cmp + (long)s * (CST * 2);
        #pragma unroll
        for (int i = 0; i < 16; ++i) pr[lane + 64 * i] = f2fp8(x[i] * inv);
    }
    __syncthreads();
    // --- PV: 8 waves; V fragments from LDS (linear ds_read_b64) ---
    int mt = wid & 1, dt = wid >> 1;  // dt in 0..3
    int srow = mt * 16 + l16; if (srow > SS - 1) srow = SS - 1;
    const uchar* ap = (const uchar*)cmp + (long)srow * (CST * 2) + quad * 8;
    const uchar* vfb = VfL + dt * 32 * 512;
    v4f a0 = {}, a1 = {}, a2 = {}, a3 = {};
    for (int k0s = 0; k0s < 32; k0s += 4) {
        a0 = __builtin_amdgcn_mfma_f32_16x16x32_fp8_fp8(
            *(const long*)(ap + k0s * 32),
            *(const long*)(vfb + k0s * 512 + lane * 8), a0, 0, 0, 0);
        a1 = __builtin_amdgcn_mfma_f32_16x16x32_fp8_fp8(
            *(const long*)(ap + (k0s + 1) * 32),
            *(const long*)(vfb + (k0s + 1) * 512 + lane * 8), a1, 0, 0, 0);
        a2 = __builtin_amdgcn_mfma_f32_16x16x32_fp8_fp8(
            *(const long*)(ap + (k0s + 2) * 32),
            *(const long*)(vfb + (k0s + 2) * 512 + lane * 8), a2, 0, 0, 0);
        a3 = __builtin_amdgcn_mfma_f32_16x16x32_fp8_fp8(
            *(const long*)(ap + (k0s + 3) * 32),
            *(const long*)(vfb + (k0s + 3) * 512 + lane * 8), a3, 0, 0, 0);
    }
    v4f accv = (a0 + a1) + (a2 + a3);
    #pragma unroll
    for (int r = 0; r < 4; ++r) {
        int s = mt * 16 + quad * 4 + r;
        if (s < SS)
            heads[((long)b * SS + s) * DD + h * 64 + dt * 16 + l16] = accv[r];
    }
}

// ---------------- K4: glimpse[1280][512] = heads @ W_out (bf16) ----------------
__global__ __launch_bounds__(256) void out_proj(const float* __restrict__ heads,
                                                const short* __restrict__ Wot,
                                                float* __restrict__ glimpse) {
    __shared__ __align__(16) short As[64 * 40], Bs[64 * 40];
    int tid = threadIdx.x;
    int m0 = blockIdx.x * 64, n0 = blockIdx.y * 64;
    int wid = tid >> 6, lane = tid & 63, quad = lane >> 4, l16 = lane & 15;
    int wm = wid & 1, wn = wid >> 1;
    int arow = tid >> 3, akol = (tid & 7) * 4;
    int brow = tid >> 2, bkol = (tid & 3) * 8;
    v4f acc[2][2] = {};
    for (int kk = 0; kk < 512; kk += 32) {
        #pragma unroll
        for (int p = 0; p < 2; ++p) {
            int r = arow + p * 32;
            v4f a = *(const v4f*)(heads + (long)(m0 + r) * 512 + kk + akol);
            short4 s4;
            s4.x = f2bf(a.x); s4.y = f2bf(a.y); s4.z = f2bf(a.z); s4.w = f2bf(a.w);
            *(short4*)(As + r * 40 + akol) = s4;
        }
        *(uint4*)(Bs + brow * 40 + bkol) =
            *(const uint4*)(Wot + (long)(n0 + brow) * 512 + kk + bkol);
        __syncthreads();
        #pragma unroll
        for (int i = 0; i < 2; ++i) {
            v8s af = *(const v8s*)(As + (wm * 32 + i * 16 + l16) * 40 + quad * 8);
            #pragma unroll
            for (int j = 0; j < 2; ++j) {
                v8s bf = *(const v8s*)(Bs + (wn * 32 + j * 16 + l16) * 40 + quad * 8);
                acc[i][j] = __builtin_amdgcn_mfma_f32_16x16x32_bf16(af, bf, acc[i][j], 0, 0, 0);
            }
        }
        __syncthreads();
    }
    #pragma unroll
    for (int i = 0; i < 2; ++i)
        #pragma unroll
        for (int j = 0; j < 2; ++j)
            #pragma unroll
            for (int r = 0; r < 4; ++r)
                glimpse[(long)(m0 + wm * 32 + i * 16 + quad * 4 + r) * 512 +
                        n0 + wn * 32 + j * 16 + l16] = acc[i][j][r];
}

// ---------------- K5: logits = (glimpse . logit_k^T)/sqrt(512)  (fp8) ----------------
__global__ __launch_bounds__(256) void ptr_logits(const float* __restrict__ glimpse,
                                                  const uchar* __restrict__ kvl8,
                                                  float* __restrict__ logits) {
    int b = blockIdx.x, g = blockIdx.y;  // g in 0..15, one n-tile per wave
    __shared__ __align__(16) uchar Gs[32 * 520];
    int tid = threadIdx.x;
    #pragma unroll
    for (int it = 0; it < 16; ++it) {
        int e = it * 1024 + tid * 4;
        int row = e >> 9, col = e & 511;
        int pk = 0;
        if (row < SS) {
            v4f a = *(const v4f*)(glimpse + ((long)b * SS + row) * 512 + col);
            pk = __builtin_amdgcn_cvt_pk_fp8_f32(a.x, a.y, 0, false);
            pk = __builtin_amdgcn_cvt_pk_fp8_f32(a.z, a.w, pk, true);
        }
        *(int*)(Gs + row * 520 + col) = pk;
    }
    __syncthreads();
    int wid = tid >> 6, lane = tid & 63, quad = lane >> 4, l16 = lane & 15;
    const float scale = 0.04419417382415922f;  // 1/sqrt(512)
    int nt = g * 4 + wid;
    int n = nt * 16 + l16;
    int ncl = n < NN ? n : NN - 1;
    const uchar* kp = kvl8 + ((long)b * NN + ncl) * 1536 + 1024 + quad * 8;
    v4f acc[2] = {};
    for (int k = 0; k < 16; ++k) {
        long bfr = *(const long*)(kp + k * 32);
        #pragma unroll
        for (int m = 0; m < 2; ++m) {
            long afr = *(const long*)(Gs + (m * 16 + l16) * 520 + k * 32 + quad * 8);
            acc[m] = __builtin_amdgcn_mfma_f32_16x16x32_fp8_fp8(afr, bfr, acc[m], 0, 0, 0);
        }
    }
    #pragma unroll
    for (int m = 0; m < 2; ++m)
        #pragma unroll
        for (int r = 0; r < 4; ++r) {
            int s = m * 16 + quad * 4 + r;
            if (s < SS)
                logits[((long)b * SS + s) * NP + nt * 16 + l16] = acc[m][r] * scale;
        }
}

// ---------------- K6: tanh clip + mask + log_softmax + (s b) transpose ----------------
__global__ __launch_bounds__(256) void logsoftmax_out(const float* __restrict__ logits,
                                                      const int* __restrict__ mask,
                                                      float* __restrict__ out) {
    int row = blockIdx.x;  // b*20 + s
    int b = row / SS, s = row % SS;
    int tid = threadIdx.x;
    __shared__ float red[8];
    int n0 = tid * 4;
    v4f v = *(const v4f*)(logits + (long)row * NP + n0);
    const int* mr = mask + (long)row * NN;
    float x[4];
    float mx = NEGV;
    #pragma unroll
    for (int j = 0; j < 4; ++j) {
        int n = n0 + j;
        float t = 10.f * tanhf(v[j]);
        bool feas = (n < NN) && (mr[n < NN ? n : 0] != 0);
        x[j] = feas ? t : NEGV;
        mx = fmaxf(mx, x[j]);
    }
    for (int off = 32; off; off >>= 1) mx = fmaxf(mx, __shfl_xor(mx, off));
    int wid = tid >> 6, lane = tid & 63;
    if (lane == 0) red[wid] = mx;
    __syncthreads();
    mx = fmaxf(fmaxf(red[0], red[1]), fmaxf(red[2], red[3]));
    float sum = 0.f;
    #pragma unroll
    for (int j = 0; j < 4; ++j) sum += __expf(x[j] - mx);
    for (int off = 32; off; off >>= 1) sum += __shfl_xor(sum, off);
    __syncthreads();
    if (lane == 0) red[4 + wid] = sum;
    __syncthreads();
    sum = red[4] + red[5] + red[6] + red[7];
    float lse = mx + __logf(sum);
    float* orow = out + ((long)s * BB + b) * NN;
    #pragma unroll
    for (int j = 0; j < 4; ++j) {
        int n = n0 + j;
        if (n < NN) orow[n] = x[j] - lse;
    }
}

extern "C" void kernel_launch(void* const* d_in, const int* in_sizes, int n_in,
                              void* d_out, int out_size, void* d_ws, size_t ws_size,
                              hipStream_t stream) {
    const float* emb  = (const float*)d_in[0];
    const float* q    = (const float*)d_in[1];
    const int*   mask = (const int*)d_in[2];
    const float* Wkvl = (const float*)d_in[3];
    const float* Wout = (const float*)d_in[4];
    float* out = (float*)d_out;

    char* ws = (char*)d_ws;
    uchar* kvl8    = (uchar*)ws; ws += (size_t)64000 * 1536;
    uchar* Wt8     = (uchar*)ws; ws += (size_t)1536 * 512;
    uchar* emb8    = (uchar*)ws; ws += (size_t)64000 * 512;
    short* Wot     = (short*)ws; ws += (size_t)512 * 512 * 2;
    float* heads   = (float*)ws; ws += (size_t)BB * SS * DD * 4;
    float* glimpse = (float*)ws; ws += (size_t)BB * SS * DD * 4;
    float* logits  = (float*)ws; ws += (size_t)BB * SS * NP * 4;

    static int s_attr_done = 0;
    if (!s_attr_done) {
        hipFuncSetAttribute(reinterpret_cast<const void*>(gemm_kvl),
                            hipFuncAttributeMaxDynamicSharedMemorySize, 65536);
        hipFuncSetAttribute(reinterpret_cast<const void*>(attn_fused),
                            hipFuncAttributeMaxDynamicSharedMemorySize, 109312);
        s_attr_done = 1;
    }

    prep<<<dim3(1024 + 16000), 256, 0, stream>>>(Wkvl, Wt8, Wout, Wot, emb, (int*)emb8);
    gemm_kvl<<<dim3(6000), 512, 65536, stream>>>(emb8, Wt8, kvl8);
    attn_fused<<<dim3(BB, HH), 512, 109312, stream>>>(q, kvl8, mask, heads);
    out_proj<<<dim3(20, 8), 256, 0, stream>>>(heads, Wot, glimpse);
    ptr_logits<<<dim3(BB, 16), 256, 0, stream>>>(glimpse, kvl8, logits);
    logsoftmax_out<<<dim3(BB * SS), 256, 0, stream>>>(logits, mask, out);
}

// Round 15
// 325.653 us; speedup vs baseline: 1.1491x; 1.0301x over previous
//
#include <hip/hip_runtime.h>

#define BB 64
#define NN 1000
#define NP 1024
#define DD 512
#define HH 8
#define SS 20
#define NEGV -1e9f

typedef float v4f __attribute__((ext_vector_type(4)));
typedef short v8s __attribute__((ext_vector_type(8)));
typedef int   v8i __attribute__((ext_vector_type(8)));
typedef int   v4i __attribute__((ext_vector_type(4)));
typedef unsigned char uchar;
typedef unsigned long long ulong_t;

static __device__ __forceinline__ short f2bf(float f) {
    unsigned u = __builtin_bit_cast(unsigned, f);
    u = (u + 0x7fffu + ((u >> 16) & 1u)) >> 16;
    return (short)u;
}
static __device__ __forceinline__ float bf2f(short s) {
    unsigned u = ((unsigned)(unsigned short)s) << 16;
    return __builtin_bit_cast(float, u);
}
static __device__ __forceinline__ uchar f2fp8(float f) {
    return (uchar)(__builtin_amdgcn_cvt_pk_fp8_f32(f, 0.f, 0, false) & 0xff);
}

// async global->LDS, 16B per lane; lds dest = wave-uniform base + lane*16
static __device__ __forceinline__ void gld16(const void* g, void* l) {
    __builtin_amdgcn_global_load_lds(
        (const __attribute__((address_space(1))) void*)(g),
        (__attribute__((address_space(3))) void*)(l),
        16, 0, 0);
}

// ---------------- K0 (merged prep): W_kvl^T->fp8, W_out^T->bf16, emb->fp8 ----------------
__global__ void prep(const float* __restrict__ Wkvl, uchar* __restrict__ Wt8,
                     const float* __restrict__ Wout, short* __restrict__ Wot,
                     const float* __restrict__ emb, int* __restrict__ emb8) {
    __shared__ float t[32][33];
    int bid = blockIdx.x, tid = threadIdx.x;
    if (bid < 768) {           // transpose_fp8: W_kvl [512][1536] -> Wt8 [1536][512]
        int c0 = (bid % 48) * 32, r0 = (bid / 48) * 32;
        int x = tid & 31, y = tid >> 5;
        for (int k = 0; k < 32; k += 8)
            t[y + k][x] = Wkvl[(long)(r0 + y + k) * 1536 + c0 + x];
        __syncthreads();
        for (int k = 0; k < 32; k += 8)
            Wt8[(long)(c0 + y + k) * 512 + r0 + x] = f2fp8(t[x][y + k]);
    } else if (bid < 1024) {   // transpose_bf16: W_out [512][512] -> Wot [512][512]
        int bb = bid - 768;
        int c0 = (bb & 15) * 32, r0 = (bb >> 4) * 32;
        int x = tid & 31, y = tid >> 5;
        for (int k = 0; k < 32; k += 8)
            t[y + k][x] = Wout[(long)(r0 + y + k) * 512 + c0 + x];
        __syncthreads();
        for (int k = 0; k < 32; k += 8)
            Wot[(long)(c0 + y + k) * 512 + r0 + x] = f2bf(t[x][y + k]);
    } else {                   // cvt_fp8: emb f32 -> fp8, 8 elems/thread
        int i = (bid - 1024) * 256 + tid;
        long o = (long)i * 8;
        v4f a = *(const v4f*)(emb + o);
        v4f b = *(const v4f*)(emb + o + 4);
        int lo = __builtin_amdgcn_cvt_pk_fp8_f32(a.x, a.y, 0, false);
        lo = __builtin_amdgcn_cvt_pk_fp8_f32(a.z, a.w, lo, true);
        int hi = __builtin_amdgcn_cvt_pk_fp8_f32(b.x, b.y, 0, false);
        hi = __builtin_amdgcn_cvt_pk_fp8_f32(b.z, b.w, hi, true);
        int2 r; r.x = lo; r.y = hi;
        *(int2*)(emb8 + i * 2) = r;
    }
}

// ---------------- K1: kvl8[64000][1536] = emb8 @ Wt8  (MX-fp8, unit scales) ----------------
// R13-proven: 128x128 tile, BK=128, 8 waves (2m x 4n), 64KiB dbuf LDS, 16 waves/CU.
__global__ __launch_bounds__(512) void gemm_kvl(const uchar* __restrict__ emb8,
                                                const uchar* __restrict__ Wt8,
                                                uchar* __restrict__ kvl8) {
    extern __shared__ __align__(16) uchar smem[];
    uchar* As0 = smem;           // 2 x 16384 (A: 128 rows x 128B)
    uchar* Bs0 = smem + 32768;   // 2 x 16384 (B: 128 rows x 128B)
    int tid = threadIdx.x;
    // XCD swizzle: nwg=6000, divisible by 8 -> simple bijective form
    int id = blockIdx.x;
    int wgid = (id & 7) * 750 + (id >> 3);
    int m_idx = wgid / 12, n_idx = wgid - m_idx * 12;
    int m0 = m_idx * 128, n0 = n_idx * 128;
    int wid = tid >> 6, lane = tid & 63, quad = lane >> 4, l16 = lane & 15;
    int wm = wid & 1, wn = wid >> 1;   // wave tile: 64(m) x 32(n); wn in 0..3
    const uchar* Ag = emb8 + (long)m0 * 512;
    const uchar* Bg = Wt8 + (long)n0 * 512;
    int rsub = lane >> 3;
    int kc = ((lane & 7) ^ rsub) * 16;   // pre-swizzled global source chunk

    v4f acc[4][2] = {};

    auto stageAB = [&](int bi, int kk) {
        #pragma unroll
        for (int p = 0; p < 2; ++p) {
            int rl = wid * 16 + p * 8;
            gld16(Ag + (long)(rl + rsub) * 512 + kk + kc, As0 + bi * 16384 + rl * 128);
        }
        #pragma unroll
        for (int p = 0; p < 2; ++p) {
            int rl = wid * 16 + p * 8;
            gld16(Bg + (long)(rl + rsub) * 512 + kk + kc, Bs0 + bi * 16384 + rl * 128);
        }
    };
    auto ldfrag = [&](const uchar* base, int row) -> v8i {
        int c0 = (quad * 2) ^ (row & 7);
        v4i lo = *(const v4i*)(base + row * 128 + c0 * 16);
        v4i hi = *(const v4i*)(base + row * 128 + (c0 ^ 1) * 16);
        return __builtin_shufflevector(lo, hi, 0, 1, 2, 3, 4, 5, 6, 7);
    };

    stageAB(0, 0);
    stageAB(1, 128);
    asm volatile("s_waitcnt vmcnt(4)" ::: "memory");   // tile-0's 4 loads done
    __builtin_amdgcn_s_barrier();
    __builtin_amdgcn_sched_barrier(0);

    v8i af[4], bf[2];
    #pragma unroll
    for (int t = 0; t < 4; ++t) {
        int cur = t & 1;
        const uchar* ab = As0 + cur * 16384;
        const uchar* bb = Bs0 + cur * 16384;
        #pragma unroll
        for (int i = 0; i < 4; ++i) af[i] = ldfrag(ab, wm * 64 + i * 16 + l16);
        #pragma unroll
        for (int j = 0; j < 2; ++j) bf[j] = ldfrag(bb, wn * 32 + j * 16 + l16);
        __builtin_amdgcn_s_setprio(1);
        #pragma unroll
        for (int i = 0; i < 4; ++i)
            acc[i][0] = __builtin_amdgcn_mfma_scale_f32_16x16x128_f8f6f4(
                af[i], bf[0], acc[i][0], 0, 0, 0, 0x7f7f7f7f, 0, 0x7f7f7f7f);
        __builtin_amdgcn_s_setprio(0);
        asm volatile("s_waitcnt lgkmcnt(0)" ::: "memory");
        __builtin_amdgcn_s_barrier();
        if (t < 2) stageAB(cur, (t + 2) * 128);
        __builtin_amdgcn_s_setprio(1);
        #pragma unroll
        for (int i = 0; i < 4; ++i)
            acc[i][1] = __builtin_amdgcn_mfma_scale_f32_16x16x128_f8f6f4(
                af[i], bf[1], acc[i][1], 0, 0, 0, 0x7f7f7f7f, 0, 0x7f7f7f7f);
        __builtin_amdgcn_s_setprio(0);
        if (t < 3) {
            if (t < 2) asm volatile("s_waitcnt vmcnt(4)" ::: "memory");
            else       asm volatile("s_waitcnt vmcnt(0)" ::: "memory");
            __builtin_amdgcn_s_barrier();
            __builtin_amdgcn_sched_barrier(0);
        }
    }
    __syncthreads();  // epilogue guard

    // epilogue: wave-private 16x32 bf16 staging (stride 40 shorts) -> 8B fp8 stores
    short* rp = (short*)smem;
    short* r = rp + wid * (16 * 40);
    int nw = n0 + wn * 32;
    #pragma unroll
    for (int i = 0; i < 4; ++i) {
        #pragma unroll
        for (int jj = 0; jj < 2; ++jj)
            #pragma unroll
            for (int rr = 0; rr < 4; ++rr)
                r[(quad * 4 + rr) * 40 + jj * 16 + l16] = f2bf(acc[i][jj][rr]);
        {
            int rowl = lane >> 2;           // 16 rows
            int colc = (lane & 3) * 8;      // 4 chunks of 8 shorts
            v8s val = *(const v8s*)(r + rowl * 40 + colc);
            int lo = __builtin_amdgcn_cvt_pk_fp8_f32(bf2f(val[0]), bf2f(val[1]), 0, false);
            lo = __builtin_amdgcn_cvt_pk_fp8_f32(bf2f(val[2]), bf2f(val[3]), lo, true);
            int hi = __builtin_amdgcn_cvt_pk_fp8_f32(bf2f(val[4]), bf2f(val[5]), 0, false);
            hi = __builtin_amdgcn_cvt_pk_fp8_f32(bf2f(val[6]), bf2f(val[7]), hi, true);
            int2 st; st.x = lo; st.y = hi;
            *(int2*)(kvl8 + (long)(m0 + wm * 64 + i * 16 + rowl) * 1536 +
                     nw + colc) = st;
        }
    }
}

// ---------------- K3: fused QK^T -> masked softmax -> V-pack -> PV ----------------
// Reordered + LDS-dieted vs R14 (65,856 B -> 2 blocks/CU):
//   regionA (45,056 B): qs+cmp during QK^T/softmax; then V scratch + VfL halves.
//   Pc (20,800 B): compact 20x1040 fp8 P (written by softmax, read by PV).
// V built in two 512-node halves AFTER softmax (cmp dead), 32KB each, overlaid on
// regionA. All component logic identical to R14-proven paths; only placement/order.
#define CST 1036  // cmp row stride (shorts): 518 words/row -> conflict-free frag reads
__global__ __launch_bounds__(512) void attn_fused(const float* __restrict__ q,
                                                  const uchar* __restrict__ kvl8,
                                                  const int* __restrict__ mask,
                                                  float* __restrict__ heads) {
    extern __shared__ __align__(16) uchar asm_[];
    uchar* qs = asm_;                       // 32*72 = 2304 (dead after QK^T)
    short* cmp = (short*)(asm_ + 2304);     // 20*1036 shorts = 41440 B (dead after softmax)
    uchar* VfL = asm_;                      // ph4: 4dt*16k0s*512 = 32768 B
    uchar* vscr = asm_ + 32768;             // ph4: 2 x [64][72] = 9216 B (ends 41984 < 45056)
    uchar* Pc = asm_ + 45056;               // 20 x 1040 B compact fp8 P
    int b = blockIdx.x, h = blockIdx.y;
    int tid = threadIdx.x, wid = tid >> 6, lane = tid & 63, quad = lane >> 4, l16 = lane & 15;

    // ---- phase 1: stage q -> qs ----
    for (int i = tid; i < 32 * 64; i += 512) {
        int row = i >> 6, col = i & 63;
        float v = (row < SS) ? q[((long)b * SS + row) * DD + h * 64 + col] : 0.f;
        qs[row * 72 + col] = f2fp8(v);
    }
    __syncthreads();

    // ---- phase 2: QK^T (fp8), /8 on f32 output; K scattered from kvl8 (R8-proven) ----
    long af[2][2];
    #pragma unroll
    for (int mt = 0; mt < 2; ++mt)
        #pragma unroll
        for (int ks = 0; ks < 2; ++ks)
            af[mt][ks] = *(const long*)(qs + (mt * 16 + l16) * 72 + ks * 32 + quad * 8);
    for (int t = 0; t < 8; ++t) {
        int nt = wid * 8 + t;
        int n = nt * 16 + l16;
        int nc = n < NN ? n : NN - 1;
        const uchar* kp = kvl8 + ((long)b * NN + nc) * 1536 + h * 64 + quad * 8;
        long b0 = *(const long*)kp;
        long b1 = *(const long*)(kp + 32);
        #pragma unroll
        for (int mt = 0; mt < 2; ++mt) {
            v4f a = {};
            a = __builtin_amdgcn_mfma_f32_16x16x32_fp8_fp8(af[mt][0], b0, a, 0, 0, 0);
            a = __builtin_amdgcn_mfma_f32_16x16x32_fp8_fp8(af[mt][1], b1, a, 0, 0, 0);
            #pragma unroll
            for (int r = 0; r < 4; ++r) {
                int s = mt * 16 + quad * 4 + r;
                if (s < SS) cmp[s * CST + nt * 16 + l16] = f2bf(a[r] * 0.125f);
            }
        }
    }
    __syncthreads();

    // ---- phase 3: masked softmax; P -> compact Pc (fp8) ----
    for (int s = wid; s < SS; s += 8) {
        const int* mr = mask + ((long)b * SS + s) * NN;
        float x[16];
        float mx = NEGV;
        #pragma unroll
        for (int i = 0; i < 16; ++i) {
            int n = lane + 64 * i;
            float v = bf2f(cmp[s * CST + n]);
            bool feas = (n < NN) && (mr[n < NN ? n : 0] != 0);
            x[i] = feas ? v : NEGV;
            mx = fmaxf(mx, x[i]);
        }
        for (int off = 32; off; off >>= 1) mx = fmaxf(mx, __shfl_xor(mx, off));
        float sum = 0.f;
        #pragma unroll
        for (int i = 0; i < 16; ++i) { x[i] = __expf(x[i] - mx); sum += x[i]; }
        for (int off = 32; off; off >>= 1) sum += __shfl_xor(sum, off);
        float inv = 1.0f / sum;
        uchar* pr = Pc + (long)s * 1040;
        #pragma unroll
        for (int i = 0; i < 16; ++i) pr[lane + 64 * i] = f2fp8(x[i] * inv);
    }
    __syncthreads();   // cmp/qs now dead -> regionA reusable

    // ---- phase 4: per-half {V-build into VfL (32KB) -> PV accumulate} ----
    int mt = wid & 1, dt = wid >> 1;  // dt in 0..3
    int srow = mt * 16 + l16; if (srow > SS - 1) srow = SS - 1;
    const uchar* ap = Pc + (long)srow * 1040 + quad * 8;
    v4f a0 = {}, a1 = {}, a2 = {}, a3 = {};
    int gsub = tid >> 8;                // 0 or 1
    int t2 = tid & 255;
    int node_l = t2 >> 2, chunk = (t2 & 3) * 16;
    int wid2 = t2 >> 6, lane2 = t2 & 63, l162 = lane2 & 15, quad2 = lane2 >> 4;
    uchar* VT = vscr + gsub * 4608;     // [64][72]
    #pragma unroll
    for (int hf = 0; hf < 2; ++hf) {
        // V-build: 8 node-groups of this half, 2 per iteration (R14-proven logic)
        for (int gg = 0; gg < 4; ++gg) {
            int gl = gg * 2 + gsub;         // local group 0..7
            int gn = (hf * 8 + gl) * 64 + node_l;
            int ncl = gn < NN ? gn : NN - 1;   // clamp: pad nodes masked by P=0 in PV
            const uchar* vp = kvl8 + ((long)b * NN + ncl) * 1536 + 512 + h * 64 + chunk;
            ulong_t v0 = *(const ulong_t*)(vp);
            ulong_t v1 = *(const ulong_t*)(vp + 8);
            uchar* b0p = (uchar*)&v0; uchar* b1p = (uchar*)&v1;
            #pragma unroll
            for (int j = 0; j < 8; ++j) VT[(chunk + j) * 72 + node_l] = b0p[j];
            #pragma unroll
            for (int j = 0; j < 8; ++j) VT[(chunk + 8 + j) * 72 + node_l] = b1p[j];
            __syncthreads();
            #pragma unroll
            for (int sub = 0; sub < 2; ++sub) {
                ulong_t frag = *(const ulong_t*)&VT[(wid2 * 16 + l162) * 72 + sub * 32 + quad2 * 8];
                *(ulong_t*)(VfL + ((wid2 * 16) + (gl * 2 + sub)) * 512 + lane2 * 8) = frag;
            }
            __syncthreads();
        }
        // PV over this half's 16 k-slices (4 independent chains)
        const uchar* vfb = VfL + dt * 16 * 512;
        for (int k0s = 0; k0s < 16; k0s += 4) {
            int kg = hf * 16 + k0s;
            a0 = __builtin_amdgcn_mfma_f32_16x16x32_fp8_fp8(
                *(const long*)(ap + (kg + 0) * 32),
                *(const long*)(vfb + (k0s + 0) * 512 + lane * 8), a0, 0, 0, 0);
            a1 = __builtin_amdgcn_mfma_f32_16x16x32_fp8_fp8(
                *(const long*)(ap + (kg + 1) * 32),
                *(const long*)(vfb + (k0s + 1) * 512 + lane * 8), a1, 0, 0, 0);
            a2 = __builtin_amdgcn_mfma_f32_16x16x32_fp8_fp8(
                *(const long*)(ap + (kg + 2) * 32),
                *(const long*)(vfb + (k0s + 2) * 512 + lane * 8), a2, 0, 0, 0);
            a3 = __builtin_amdgcn_mfma_f32_16x16x32_fp8_fp8(
                *(const long*)(ap + (kg + 3) * 32),
                *(const long*)(vfb + (k0s + 3) * 512 + lane * 8), a3, 0, 0, 0);
        }
        __syncthreads();   // protect VfL before next half's build (lgkm drained by barrier)
    }
    v4f accv = (a0 + a1) + (a2 + a3);
    #pragma unroll
    for (int r = 0; r < 4; ++r) {
        int s = mt * 16 + quad * 4 + r;
        if (s < SS)
            heads[((long)b * SS + s) * DD + h * 64 + dt * 16 + l16] = accv[r];
    }
}

// ---------------- K4: glimpse[1280][512] = heads @ W_out (bf16) ----------------
__global__ __launch_bounds__(256) void out_proj(const float* __restrict__ heads,
                                                const short* __restrict__ Wot,
                                                float* __restrict__ glimpse) {
    __shared__ __align__(16) short As[64 * 40], Bs[64 * 40];
    int tid = threadIdx.x;
    int m0 = blockIdx.x * 64, n0 = blockIdx.y * 64;
    int wid = tid >> 6, lane = tid & 63, quad = lane >> 4, l16 = lane & 15;
    int wm = wid & 1, wn = wid >> 1;
    int arow = tid >> 3, akol = (tid & 7) * 4;
    int brow = tid >> 2, bkol = (tid & 3) * 8;
    v4f acc[2][2] = {};
    for (int kk = 0; kk < 512; kk += 32) {
        #pragma unroll
        for (int p = 0; p < 2; ++p) {
            int r = arow + p * 32;
            v4f a = *(const v4f*)(heads + (long)(m0 + r) * 512 + kk + akol);
            short4 s4;
            s4.x = f2bf(a.x); s4.y = f2bf(a.y); s4.z = f2bf(a.z); s4.w = f2bf(a.w);
            *(short4*)(As + r * 40 + akol) = s4;
        }
        *(uint4*)(Bs + brow * 40 + bkol) =
            *(const uint4*)(Wot + (long)(n0 + brow) * 512 + kk + bkol);
        __syncthreads();
        #pragma unroll
        for (int i = 0; i < 2; ++i) {
            v8s af = *(const v8s*)(As + (wm * 32 + i * 16 + l16) * 40 + quad * 8);
            #pragma unroll
            for (int j = 0; j < 2; ++j) {
                v8s bf = *(const v8s*)(Bs + (wn * 32 + j * 16 + l16) * 40 + quad * 8);
                acc[i][j] = __builtin_amdgcn_mfma_f32_16x16x32_bf16(af, bf, acc[i][j], 0, 0, 0);
            }
        }
        __syncthreads();
    }
    #pragma unroll
    for (int i = 0; i < 2; ++i)
        #pragma unroll
        for (int j = 0; j < 2; ++j)
            #pragma unroll
            for (int r = 0; r < 4; ++r)
                glimpse[(long)(m0 + wm * 32 + i * 16 + quad * 4 + r) * 512 +
                        n0 + wn * 32 + j * 16 + l16] = acc[i][j][r];
}

// ---------------- K5: logits = (glimpse . logit_k^T)/sqrt(512)  (fp8) ----------------
__global__ __launch_bounds__(256) void ptr_logits(const float* __restrict__ glimpse,
                                                  const uchar* __restrict__ kvl8,
                                                  float* __restrict__ logits) {
    int b = blockIdx.x, g = blockIdx.y;  // g in 0..15, one n-tile per wave
    __shared__ __align__(16) uchar Gs[32 * 520];
    int tid = threadIdx.x;
    #pragma unroll
    for (int it = 0; it < 16; ++it) {
        int e = it * 1024 + tid * 4;
        int row = e >> 9, col = e & 511;
        int pk = 0;
        if (row < SS) {
            v4f a = *(const v4f*)(glimpse + ((long)b * SS + row) * 512 + col);
            pk = __builtin_amdgcn_cvt_pk_fp8_f32(a.x, a.y, 0, false);
            pk = __builtin_amdgcn_cvt_pk_fp8_f32(a.z, a.w, pk, true);
        }
        *(int*)(Gs + row * 520 + col) = pk;
    }
    __syncthreads();
    int wid = tid >> 6, lane = tid & 63, quad = lane >> 4, l16 = lane & 15;
    const float scale = 0.04419417382415922f;  // 1/sqrt(512)
    int nt = g * 4 + wid;
    int n = nt * 16 + l16;
    int ncl = n < NN ? n : NN - 1;
    const uchar* kp = kvl8 + ((long)b * NN + ncl) * 1536 + 1024 + quad * 8;
    v4f acc[2] = {};
    for (int k = 0; k < 16; ++k) {
        long bfr = *(const long*)(kp + k * 32);
        #pragma unroll
        for (int m = 0; m < 2; ++m) {
            long afr = *(const long*)(Gs + (m * 16 + l16) * 520 + k * 32 + quad * 8);
            acc[m] = __builtin_amdgcn_mfma_f32_16x16x32_fp8_fp8(afr, bfr, acc[m], 0, 0, 0);
        }
    }
    #pragma unroll
    for (int m = 0; m < 2; ++m)
        #pragma unroll
        for (int r = 0; r < 4; ++r) {
            int s = m * 16 + quad * 4 + r;
            if (s < SS)
                logits[((long)b * SS + s) * NP + nt * 16 + l16] = acc[m][r] * scale;
        }
}

// ---------------- K6: tanh clip + mask + log_softmax + (s b) transpose ----------------
__global__ __launch_bounds__(256) void logsoftmax_out(const float* __restrict__ logits,
                                                      const int* __restrict__ mask,
                                                      float* __restrict__ out) {
    int row = blockIdx.x;  // b*20 + s
    int b = row / SS, s = row % SS;
    int tid = threadIdx.x;
    __shared__ float red[8];
    int n0 = tid * 4;
    v4f v = *(const v4f*)(logits + (long)row * NP + n0);
    const int* mr = mask + (long)row * NN;
    float x[4];
    float mx = NEGV;
    #pragma unroll
    for (int j = 0; j < 4; ++j) {
        int n = n0 + j;
        float t = 10.f * tanhf(v[j]);
        bool feas = (n < NN) && (mr[n < NN ? n : 0] != 0);
        x[j] = feas ? t : NEGV;
        mx = fmaxf(mx, x[j]);
    }
    for (int off = 32; off; off >>= 1) mx = fmaxf(mx, __shfl_xor(mx, off));
    int wid = tid >> 6, lane = tid & 63;
    if (lane == 0) red[wid] = mx;
    __syncthreads();
    mx = fmaxf(fmaxf(red[0], red[1]), fmaxf(red[2], red[3]));
    float sum = 0.f;
    #pragma unroll
    for (int j = 0; j < 4; ++j) sum += __expf(x[j] - mx);
    for (int off = 32; off; off >>= 1) sum += __shfl_xor(sum, off);
    __syncthreads();
    if (lane == 0) red[4 + wid] = sum;
    __syncthreads();
    sum = red[4] + red[5] + red[6] + red[7];
    float lse = mx + __logf(sum);
    float* orow = out + ((long)s * BB + b) * NN;
    #pragma unroll
    for (int j = 0; j < 4; ++j) {
        int n = n0 + j;
        if (n < NN) orow[n] = x[j] - lse;
    }
}

extern "C" void kernel_launch(void* const* d_in, const int* in_sizes, int n_in,
                              void* d_out, int out_size, void* d_ws, size_t ws_size,
                              hipStream_t stream) {
    const float* emb  = (const float*)d_in[0];
    const float* q    = (const float*)d_in[1];
    const int*   mask = (const int*)d_in[2];
    const float* Wkvl = (const float*)d_in[3];
    const float* Wout = (const float*)d_in[4];
    float* out = (float*)d_out;

    char* ws = (char*)d_ws;
    uchar* kvl8    = (uchar*)ws; ws += (size_t)64000 * 1536;
    uchar* Wt8     = (uchar*)ws; ws += (size_t)1536 * 512;
    uchar* emb8    = (uchar*)ws; ws += (size_t)64000 * 512;
    short* Wot     = (short*)ws; ws += (size_t)512 * 512 * 2;
    float* heads   = (float*)ws; ws += (size_t)BB * SS * DD * 4;
    float* glimpse = (float*)ws; ws += (size_t)BB * SS * DD * 4;
    float* logits  = (float*)ws; ws += (size_t)BB * SS * NP * 4;

    static int s_attr_done = 0;
    if (!s_attr_done) {
        hipFuncSetAttribute(reinterpret_cast<const void*>(gemm_kvl),
                            hipFuncAttributeMaxDynamicSharedMemorySize, 65536);
        hipFuncSetAttribute(reinterpret_cast<const void*>(attn_fused),
                            hipFuncAttributeMaxDynamicSharedMemorySize, 65856);
        s_attr_done = 1;
    }

    prep<<<dim3(1024 + 16000), 256, 0, stream>>>(Wkvl, Wt8, Wout, Wot, emb, (int*)emb8);
    gemm_kvl<<<dim3(6000), 512, 65536, stream>>>(emb8, Wt8, kvl8);
    attn_fused<<<dim3(BB, HH), 512, 65856, stream>>>(q, kvl8, mask, heads);
    out_proj<<<dim3(20, 8), 256, 0, stream>>>(heads, Wot, glimpse);
    ptr_logits<<<dim3(BB, 16), 256, 0, stream>>>(glimpse, kvl8, logits);
    logsoftmax_out<<<dim3(BB * SS), 256, 0, stream>>>(logits, mask, out);
}